// Round 1
// baseline (950.722 us; speedup 1.0000x reference)
//
#include <hip/hip_runtime.h>
#include <hip/hip_bf16.h>

// ---------------------------------------------------------------------------
// GCN: h1 = lrelu(GCNConv(x; W1,b1)); h2 = lrelu(GCNConv(h1; W2,b2));
//      g = segment_mean(h2, batch); MLP head W3/W4/W5.
// Strategy: CSR-by-dst built per launch (deg -> scan -> fill), gather-based
// aggregation (no float atomics), fp32 register-blocked GEMMs.
// ---------------------------------------------------------------------------

#define SLOPE 0.01f

__device__ __forceinline__ float lrelu(float x) { return x > 0.f ? x : SLOPE * x; }

// ---- setup kernels --------------------------------------------------------

__global__ void k_zero_i32(int* __restrict__ a, int n) {
    int i = blockIdx.x * 256 + threadIdx.x;
    if (i < n) a[i] = 0;
}

__global__ void k_count(const int* __restrict__ dst, int* __restrict__ degi, int E) {
    int e = blockIdx.x * 256 + threadIdx.x;
    if (e < E) atomicAdd(&degi[dst[e]], 1);
}

__global__ void k_dinv(const int* __restrict__ degi, float* __restrict__ dinv, int N) {
    int i = blockIdx.x * 256 + threadIdx.x;
    if (i < N) dinv[i] = rsqrtf((float)degi[i] + 1.0f);
}

// exclusive scan of degi -> rp (3 kernels)
__global__ void k_scan1(const int* __restrict__ degi, int* __restrict__ rp,
                        int* __restrict__ bsum, int N) {
    __shared__ int s[256];
    int t = threadIdx.x;
    int i = blockIdx.x * 256 + t;
    int v = (i < N) ? degi[i] : 0;
    s[t] = v;
    __syncthreads();
    for (int off = 1; off < 256; off <<= 1) {
        int add = (t >= off) ? s[t - off] : 0;
        __syncthreads();
        s[t] += add;
        __syncthreads();
    }
    if (i < N) rp[i] = s[t] - v;               // exclusive within block
    if (t == 255) bsum[blockIdx.x] = s[255];   // block total
}

__global__ void k_scan2(int* __restrict__ bsum, int nb) {
    __shared__ int s[512];
    int t = threadIdx.x;
    int v = (t < nb) ? bsum[t] : 0;
    s[t] = v;
    __syncthreads();
    for (int off = 1; off < 512; off <<= 1) {
        int add = (t >= off) ? s[t - off] : 0;
        __syncthreads();
        s[t] += add;
        __syncthreads();
    }
    if (t < nb) bsum[t] = s[t] - v;            // exclusive
}

__global__ void k_scan3(int* __restrict__ rp, const int* __restrict__ bsum, int N, int E) {
    int i = blockIdx.x * 256 + threadIdx.x;
    if (i < N) rp[i] += bsum[blockIdx.x];
    if (blockIdx.x == 0 && threadIdx.x == 0) rp[N] = E;
}

__global__ void k_fill(const int* __restrict__ src, const int* __restrict__ dst,
                       const int* __restrict__ rp, int* __restrict__ cnt,
                       int* __restrict__ csr_src, int E) {
    int e = blockIdx.x * 256 + threadIdx.x;
    if (e < E) {
        int d = dst[e];
        int pos = rp[d] + atomicAdd(&cnt[d], 1);
        csr_src[pos] = src[e];
    }
}

// ---- dense GEMM: Y[M,128] = X[M,128] @ W[128,128]  (fp32, no bias) --------
// 256 threads, 32 rows/block, 4x4 register tile per thread.
// W staged in LDS in two 64-row phases to stay under 64KB static LDS.
__global__ __launch_bounds__(256) void k_gemm128(const float* __restrict__ X,
                                                 const float* __restrict__ W,
                                                 float* __restrict__ Y, int M) {
    __shared__ float Ws[64 * 128];     // 32 KB
    __shared__ float Xs[32][129];      // 16.5 KB (pad breaks bank aliasing)
    int t = threadIdx.x;
    size_t row0 = (size_t)blockIdx.x * 32;

    const float4* X4 = (const float4*)(X + row0 * 128);
#pragma unroll
    for (int i = 0; i < 4; ++i) {
        int idx = t + i * 256;         // 0..1023 float4s = 32 rows * 32 f4
        float4 v = X4[idx];
        int r = idx >> 5, c4 = idx & 31;
        float* dp = &Xs[r][c4 * 4];
        dp[0] = v.x; dp[1] = v.y; dp[2] = v.z; dp[3] = v.w;
    }

    int cg = t & 31;    // column group: cols cg*4 .. cg*4+3
    int rg = t >> 5;    // 0..7: rows rg*4 .. rg*4+3
    float acc[4][4] = {{0.f}};

    const float4* W4p = (const float4*)W;
    float4* Ws4 = (float4*)Ws;
    for (int kp = 0; kp < 2; ++kp) {
        __syncthreads();
#pragma unroll
        for (int i = 0; i < 8; ++i) Ws4[t + i * 256] = W4p[kp * 2048 + t + i * 256];
        __syncthreads();
#pragma unroll 8
        for (int k = 0; k < 64; ++k) {
            float4 wv = *(const float4*)&Ws[k * 128 + cg * 4];
            int kk = kp * 64 + k;
#pragma unroll
            for (int i = 0; i < 4; ++i) {
                float xv = Xs[rg * 4 + i][kk];
                acc[i][0] += xv * wv.x;
                acc[i][1] += xv * wv.y;
                acc[i][2] += xv * wv.z;
                acc[i][3] += xv * wv.w;
            }
        }
    }
#pragma unroll
    for (int i = 0; i < 4; ++i) {
        size_t r = row0 + rg * 4 + i;
        float4 v = make_float4(acc[i][0], acc[i][1], acc[i][2], acc[i][3]);
        *(float4*)&Y[r * 128 + cg * 4] = v;
    }
}

// ---- aggregation: OUT[u] = lrelu( sum_{s in N(u)} H[s]*dinv[s]*dinv[u]
//                                   + H[u]*dinv[u]^2 + bias )
// one node per 128-thread block; coalesced 512B row gathers, no atomics.
__global__ __launch_bounds__(128) void k_agg(const float* __restrict__ H,
                                             const int* __restrict__ csr_src,
                                             const int* __restrict__ rp,
                                             const float* __restrict__ dinv,
                                             const float* __restrict__ bias,
                                             float* __restrict__ OUT, int N) {
    int u = blockIdx.x;
    int c = threadIdx.x;
    float du = dinv[u];
    float acc = H[(size_t)u * 128 + c] * du * du;   // self-loop term 1/deg
    int e0 = rp[u], e1 = rp[u + 1];
    for (int e = e0; e < e1; ++e) {
        int s = csr_src[e];
        float w = dinv[s] * du;
        acc += H[(size_t)s * 128 + c] * w;
    }
    acc += bias[c];
    OUT[(size_t)u * 128 + c] = lrelu(acc);
}

// ---- global mean pool: one graph per 128-thread block ---------------------
__global__ __launch_bounds__(128) void k_pool(const float* __restrict__ H,
                                              const int* __restrict__ batch,
                                              float* __restrict__ G, int N) {
    int g = blockIdx.x;
    int c = threadIdx.x;
    // lower_bound(batch, g) and lower_bound(batch, g+1); batch is sorted
    int lo = 0, hi = N;
    while (lo < hi) { int mid = (lo + hi) >> 1; if (batch[mid] < g) lo = mid + 1; else hi = mid; }
    int start = lo;
    hi = N;
    while (lo < hi) { int mid = (lo + hi) >> 1; if (batch[mid] < g + 1) lo = mid + 1; else hi = mid; }
    int end = lo;
    float acc = 0.f;
    for (int n = start; n < end; ++n) acc += H[(size_t)n * 128 + c];
    float cntf = (float)(end - start);
    G[g * 128 + c] = acc / fmaxf(cntf, 1.0f);
}

// ---- fused MLP head: one graph per 64-thread block ------------------------
__global__ __launch_bounds__(64) void k_mlp(const float* __restrict__ G,
                                            const float* __restrict__ W3, const float* __restrict__ b3,
                                            const float* __restrict__ W4, const float* __restrict__ b4,
                                            const float* __restrict__ W5, const float* __restrict__ b5,
                                            float* __restrict__ OUT) {
    __shared__ float row[128];
    __shared__ float t1[64];
    __shared__ float t2[64];
    int g = blockIdx.x, t = threadIdx.x;
    row[t] = G[g * 128 + t];
    row[t + 64] = G[g * 128 + t + 64];
    __syncthreads();
    float acc = b3[t];
    for (int k = 0; k < 128; ++k) acc += row[k] * W3[k * 64 + t];
    t1[t] = lrelu(acc);
    __syncthreads();
    acc = b4[t];
    for (int k = 0; k < 64; ++k) acc += t1[k] * W4[k * 64 + t];
    t2[t] = lrelu(acc);
    __syncthreads();
    if (t < 10) {
        acc = b5[t];
        for (int k = 0; k < 64; ++k) acc += t2[k] * W5[k * 10 + t];
        OUT[g * 10 + t] = acc;
    }
}

// ---------------------------------------------------------------------------

extern "C" void kernel_launch(void* const* d_in, const int* in_sizes, int n_in,
                              void* d_out, int out_size, void* d_ws, size_t ws_size,
                              hipStream_t stream) {
    const float* x    = (const float*)d_in[0];
    const int*   ei   = (const int*)d_in[1];   // [2, E] int32
    const int*   batch= (const int*)d_in[2];
    const float* W1   = (const float*)d_in[3];
    const float* b1   = (const float*)d_in[4];
    const float* W2   = (const float*)d_in[5];
    const float* b2   = (const float*)d_in[6];
    const float* W3   = (const float*)d_in[7];
    const float* b3   = (const float*)d_in[8];
    const float* W4   = (const float*)d_in[9];
    const float* b4   = (const float*)d_in[10];
    const float* W5   = (const float*)d_in[11];
    const float* b5   = (const float*)d_in[12];
    float* out = (float*)d_out;

    const int N = in_sizes[2];          // 100000
    const int E = in_sizes[1] / 2;      // 1600000
    const int NG = 128;                 // NUM_GRAPHS

    const int* src = ei;
    const int* dst = ei + E;

    // workspace carve-up
    char* w = (char*)d_ws;
    float* bufA = (float*)w; w += (size_t)N * 128 * 4;   // 51.2 MB
    float* bufB = (float*)w; w += (size_t)N * 128 * 4;   // 51.2 MB
    int*   degi = (int*)w;   w += (size_t)N * 4;
    int*   cnt  = (int*)w;   w += (size_t)N * 4;
    float* dinv = (float*)w; w += (size_t)N * 4;
    int*   rp   = (int*)w;   w += (size_t)(N + 8) * 4;
    int*   bsum = (int*)w;   w += 512 * 4;
    int*   csr  = (int*)w;   w += (size_t)E * 4;         // 6.4 MB
    float* g    = (float*)w; w += 128 * 128 * 4;
    (void)ws_size; (void)n_in; (void)out_size;

    int nbN  = (N + 255) / 256;       // 391
    int nbE  = (E + 255) / 256;       // 6250
    int nb2N = (2 * N + 255) / 256;

    // CSR build (degi and cnt are contiguous -> zero both in one launch)
    k_zero_i32<<<nb2N, 256, 0, stream>>>(degi, 2 * N);
    k_count<<<nbE, 256, 0, stream>>>(dst, degi, E);
    k_dinv<<<nbN, 256, 0, stream>>>(degi, dinv, N);
    k_scan1<<<nbN, 256, 0, stream>>>(degi, rp, bsum, N);
    k_scan2<<<1, 512, 0, stream>>>(bsum, nbN);
    k_scan3<<<nbN, 256, 0, stream>>>(rp, bsum, N, E);
    k_fill<<<nbE, 256, 0, stream>>>(src, dst, rp, cnt, csr, E);

    // layer 1
    k_gemm128<<<N / 32, 256, 0, stream>>>(x, W1, bufA, N);
    k_agg<<<N, 128, 0, stream>>>(bufA, csr, rp, dinv, b1, bufB, N);
    // layer 2
    k_gemm128<<<N / 32, 256, 0, stream>>>(bufB, W2, bufA, N);
    k_agg<<<N, 128, 0, stream>>>(bufA, csr, rp, dinv, b2, bufB, N);

    // pool + MLP head
    k_pool<<<NG, 128, 0, stream>>>(bufB, batch, g, N);
    k_mlp<<<NG, 64, 0, stream>>>(g, W3, b3, W4, b4, W5, b5, out);
}

// Round 2
// 829.583 us; speedup vs baseline: 1.1460x; 1.1460x over previous
//
#include <hip/hip_runtime.h>
#include <hip/hip_bf16.h>

// ---------------------------------------------------------------------------
// GCN: h1 = lrelu(GCNConv(x; W1,b1)); h2 = lrelu(GCNConv(h1; W2,b2));
//      g = segment_mean(h2, batch); MLP head W3/W4/W5.
// R1: node-parallel pooling (was: 1 block/graph serial scan, 213us @2.5% occ).
// ---------------------------------------------------------------------------

#define SLOPE 0.01f

__device__ __forceinline__ float lrelu(float x) { return x > 0.f ? x : SLOPE * x; }

// ---- setup kernels --------------------------------------------------------

__global__ void k_zero_i32(int* __restrict__ a, int n) {
    int i = blockIdx.x * 256 + threadIdx.x;
    if (i < n) a[i] = 0;
}

__global__ void k_count(const int* __restrict__ dst, int* __restrict__ degi, int E) {
    int e = blockIdx.x * 256 + threadIdx.x;
    if (e < E) atomicAdd(&degi[dst[e]], 1);
}

__global__ void k_dinv(const int* __restrict__ degi, float* __restrict__ dinv, int N) {
    int i = blockIdx.x * 256 + threadIdx.x;
    if (i < N) dinv[i] = rsqrtf((float)degi[i] + 1.0f);
}

// exclusive scan of degi -> rp (3 kernels)
__global__ void k_scan1(const int* __restrict__ degi, int* __restrict__ rp,
                        int* __restrict__ bsum, int N) {
    __shared__ int s[256];
    int t = threadIdx.x;
    int i = blockIdx.x * 256 + t;
    int v = (i < N) ? degi[i] : 0;
    s[t] = v;
    __syncthreads();
    for (int off = 1; off < 256; off <<= 1) {
        int add = (t >= off) ? s[t - off] : 0;
        __syncthreads();
        s[t] += add;
        __syncthreads();
    }
    if (i < N) rp[i] = s[t] - v;               // exclusive within block
    if (t == 255) bsum[blockIdx.x] = s[255];   // block total
}

__global__ void k_scan2(int* __restrict__ bsum, int nb) {
    __shared__ int s[512];
    int t = threadIdx.x;
    int v = (t < nb) ? bsum[t] : 0;
    s[t] = v;
    __syncthreads();
    for (int off = 1; off < 512; off <<= 1) {
        int add = (t >= off) ? s[t - off] : 0;
        __syncthreads();
        s[t] += add;
        __syncthreads();
    }
    if (t < nb) bsum[t] = s[t] - v;            // exclusive
}

__global__ void k_scan3(int* __restrict__ rp, const int* __restrict__ bsum, int N, int E) {
    int i = blockIdx.x * 256 + threadIdx.x;
    if (i < N) rp[i] += bsum[blockIdx.x];
    if (blockIdx.x == 0 && threadIdx.x == 0) rp[N] = E;
}

__global__ void k_fill(const int* __restrict__ src, const int* __restrict__ dst,
                       const int* __restrict__ rp, int* __restrict__ cnt,
                       int* __restrict__ csr_src, int E) {
    int e = blockIdx.x * 256 + threadIdx.x;
    if (e < E) {
        int d = dst[e];
        int pos = rp[d] + atomicAdd(&cnt[d], 1);
        csr_src[pos] = src[e];
    }
}

// ---- dense GEMM: Y[M,128] = X[M,128] @ W[128,128]  (fp32, no bias) --------
__global__ __launch_bounds__(256) void k_gemm128(const float* __restrict__ X,
                                                 const float* __restrict__ W,
                                                 float* __restrict__ Y, int M) {
    __shared__ float Ws[64 * 128];     // 32 KB
    __shared__ float Xs[32][129];      // 16.5 KB
    int t = threadIdx.x;
    size_t row0 = (size_t)blockIdx.x * 32;

    const float4* X4 = (const float4*)(X + row0 * 128);
#pragma unroll
    for (int i = 0; i < 4; ++i) {
        int idx = t + i * 256;
        float4 v = X4[idx];
        int r = idx >> 5, c4 = idx & 31;
        float* dp = &Xs[r][c4 * 4];
        dp[0] = v.x; dp[1] = v.y; dp[2] = v.z; dp[3] = v.w;
    }

    int cg = t & 31;
    int rg = t >> 5;
    float acc[4][4] = {{0.f}};

    const float4* W4p = (const float4*)W;
    float4* Ws4 = (float4*)Ws;
    for (int kp = 0; kp < 2; ++kp) {
        __syncthreads();
#pragma unroll
        for (int i = 0; i < 8; ++i) Ws4[t + i * 256] = W4p[kp * 2048 + t + i * 256];
        __syncthreads();
#pragma unroll 8
        for (int k = 0; k < 64; ++k) {
            float4 wv = *(const float4*)&Ws[k * 128 + cg * 4];
            int kk = kp * 64 + k;
#pragma unroll
            for (int i = 0; i < 4; ++i) {
                float xv = Xs[rg * 4 + i][kk];
                acc[i][0] += xv * wv.x;
                acc[i][1] += xv * wv.y;
                acc[i][2] += xv * wv.z;
                acc[i][3] += xv * wv.w;
            }
        }
    }
#pragma unroll
    for (int i = 0; i < 4; ++i) {
        size_t r = row0 + rg * 4 + i;
        float4 v = make_float4(acc[i][0], acc[i][1], acc[i][2], acc[i][3]);
        *(float4*)&Y[r * 128 + cg * 4] = v;
    }
}

// ---- aggregation: OUT[u] = lrelu( sum_{s in N(u)} H[s]*dinv[s]*dinv[u]
//                                   + H[u]*dinv[u]^2 + bias )
__global__ __launch_bounds__(128) void k_agg(const float* __restrict__ H,
                                             const int* __restrict__ csr_src,
                                             const int* __restrict__ rp,
                                             const float* __restrict__ dinv,
                                             const float* __restrict__ bias,
                                             float* __restrict__ OUT, int N) {
    int u = blockIdx.x;
    int c = threadIdx.x;
    float du = dinv[u];
    float acc = H[(size_t)u * 128 + c] * du * du;   // self-loop term 1/deg
    int e0 = rp[u], e1 = rp[u + 1];
    for (int e = e0; e < e1; ++e) {
        int s = csr_src[e];
        float w = dinv[s] * du;
        acc += H[(size_t)s * 128 + c] * w;
    }
    acc += bias[c];
    OUT[(size_t)u * 128 + c] = lrelu(acc);
}

// ---- global mean pool, node-parallel --------------------------------------
// Each block streams CHUNK consecutive nodes; batch is sorted, so runs of the
// same graph accumulate in registers and flush via atomicAdd on graph change.
#define POOL_CHUNK 256
__global__ __launch_bounds__(128) void k_pool2(const float* __restrict__ H,
                                               const int* __restrict__ batch,
                                               float* __restrict__ Gsum,
                                               int* __restrict__ Gcnt, int N) {
    int n0 = blockIdx.x * POOL_CHUNK;
    int n1 = n0 + POOL_CHUNK; if (n1 > N) n1 = N;
    if (n0 >= N) return;
    int c = threadIdx.x;
    float acc = 0.f;
    int cur = batch[n0];
    int runstart = n0;
    for (int n = n0; n < n1; ++n) {
        int g = batch[n];                      // broadcast load
        if (g != cur) {
            atomicAdd(&Gsum[cur * 128 + c], acc);
            if (c == 0) atomicAdd(&Gcnt[cur], n - runstart);
            acc = 0.f; cur = g; runstart = n;
        }
        acc += H[(size_t)n * 128 + c];
    }
    atomicAdd(&Gsum[cur * 128 + c], acc);
    if (c == 0) atomicAdd(&Gcnt[cur], n1 - runstart);
}

// ---- fused MLP head (divide-by-count folded in): one graph per block ------
__global__ __launch_bounds__(64) void k_mlp(const float* __restrict__ Gsum,
                                            const int* __restrict__ Gcnt,
                                            const float* __restrict__ W3, const float* __restrict__ b3,
                                            const float* __restrict__ W4, const float* __restrict__ b4,
                                            const float* __restrict__ W5, const float* __restrict__ b5,
                                            float* __restrict__ OUT) {
    __shared__ float row[128];
    __shared__ float t1[64];
    __shared__ float t2[64];
    int g = blockIdx.x, t = threadIdx.x;
    float inv = 1.0f / fmaxf((float)Gcnt[g], 1.0f);
    row[t]      = Gsum[g * 128 + t] * inv;
    row[t + 64] = Gsum[g * 128 + t + 64] * inv;
    __syncthreads();
    float acc = b3[t];
    for (int k = 0; k < 128; ++k) acc += row[k] * W3[k * 64 + t];
    t1[t] = lrelu(acc);
    __syncthreads();
    acc = b4[t];
    for (int k = 0; k < 64; ++k) acc += t1[k] * W4[k * 64 + t];
    t2[t] = lrelu(acc);
    __syncthreads();
    if (t < 10) {
        acc = b5[t];
        for (int k = 0; k < 64; ++k) acc += t2[k] * W5[k * 10 + t];
        OUT[g * 10 + t] = acc;
    }
}

// ---------------------------------------------------------------------------

extern "C" void kernel_launch(void* const* d_in, const int* in_sizes, int n_in,
                              void* d_out, int out_size, void* d_ws, size_t ws_size,
                              hipStream_t stream) {
    const float* x    = (const float*)d_in[0];
    const int*   ei   = (const int*)d_in[1];   // [2, E] int32
    const int*   batch= (const int*)d_in[2];
    const float* W1   = (const float*)d_in[3];
    const float* b1   = (const float*)d_in[4];
    const float* W2   = (const float*)d_in[5];
    const float* b2   = (const float*)d_in[6];
    const float* W3   = (const float*)d_in[7];
    const float* b3   = (const float*)d_in[8];
    const float* W4   = (const float*)d_in[9];
    const float* b4   = (const float*)d_in[10];
    const float* W5   = (const float*)d_in[11];
    const float* b5   = (const float*)d_in[12];
    float* out = (float*)d_out;

    const int N = in_sizes[2];          // 100000
    const int E = in_sizes[1] / 2;      // 1600000
    const int NG = 128;                 // NUM_GRAPHS

    const int* src = ei;
    const int* dst = ei + E;

    // workspace carve-up  (degi, cnt, gsum, gcnt contiguous -> one zero pass)
    char* w = (char*)d_ws;
    float* bufA = (float*)w; w += (size_t)N * 128 * 4;   // 51.2 MB
    float* bufB = (float*)w; w += (size_t)N * 128 * 4;   // 51.2 MB
    int*   degi = (int*)w;   w += (size_t)N * 4;
    int*   cnt  = (int*)w;   w += (size_t)N * 4;
    float* gsum = (float*)w; w += (size_t)NG * 128 * 4;  // 64 KB
    int*   gcnt = (int*)w;   w += (size_t)NG * 4;
    float* dinv = (float*)w; w += (size_t)N * 4;
    int*   rp   = (int*)w;   w += (size_t)(N + 8) * 4;
    int*   bsum = (int*)w;   w += 512 * 4;
    int*   csr  = (int*)w;   w += (size_t)E * 4;         // 6.4 MB
    (void)ws_size; (void)n_in; (void)out_size;

    int nbN  = (N + 255) / 256;       // 391
    int nbE  = (E + 255) / 256;       // 6250
    int nZero = 2 * N + NG * 128 + NG;
    int nbZ  = (nZero + 255) / 256;

    // CSR build + pool-accumulator zeroing (one contiguous zero pass)
    k_zero_i32<<<nbZ, 256, 0, stream>>>(degi, nZero);
    k_count<<<nbE, 256, 0, stream>>>(dst, degi, E);
    k_dinv<<<nbN, 256, 0, stream>>>(degi, dinv, N);
    k_scan1<<<nbN, 256, 0, stream>>>(degi, rp, bsum, N);
    k_scan2<<<1, 512, 0, stream>>>(bsum, nbN);
    k_scan3<<<nbN, 256, 0, stream>>>(rp, bsum, N, E);
    k_fill<<<nbE, 256, 0, stream>>>(src, dst, rp, cnt, csr, E);

    // layer 1
    k_gemm128<<<N / 32, 256, 0, stream>>>(x, W1, bufA, N);
    k_agg<<<N, 128, 0, stream>>>(bufA, csr, rp, dinv, b1, bufB, N);
    // layer 2
    k_gemm128<<<N / 32, 256, 0, stream>>>(bufB, W2, bufA, N);
    k_agg<<<N, 128, 0, stream>>>(bufA, csr, rp, dinv, b2, bufB, N);

    // pool + MLP head
    int nbP = (N + POOL_CHUNK - 1) / POOL_CHUNK;
    k_pool2<<<nbP, 128, 0, stream>>>(bufB, batch, gsum, gcnt, N);
    k_mlp<<<NG, 64, 0, stream>>>(gsum, gcnt, W3, b3, W4, b4, W5, b5, out);
}

// Round 3
// 735.338 us; speedup vs baseline: 1.2929x; 1.1282x over previous
//
#include <hip/hip_runtime.h>
#include <hip/hip_bf16.h>

// ---------------------------------------------------------------------------
// GCN: h1 = lrelu(GCNConv(x; W1,b1)); h2 = lrelu(GCNConv(h1; W2,b2));
//      g = segment_mean(h2, batch); MLP head W3/W4/W5.
// R1: node-parallel pooling (was: 213us @2.5% occ -> ~15us).
// R2: k_agg 8-way edge-parallel float4 gathers (was: serial edge loop,
//     183us @2.7TB/s latency-bound).
// ---------------------------------------------------------------------------

#define SLOPE 0.01f

__device__ __forceinline__ float lrelu(float x) { return x > 0.f ? x : SLOPE * x; }

// ---- setup kernels --------------------------------------------------------

__global__ void k_zero_i32(int* __restrict__ a, int n) {
    int i = blockIdx.x * 256 + threadIdx.x;
    if (i < n) a[i] = 0;
}

__global__ void k_count(const int* __restrict__ dst, int* __restrict__ degi, int E) {
    int e = blockIdx.x * 256 + threadIdx.x;
    if (e < E) atomicAdd(&degi[dst[e]], 1);
}

__global__ void k_dinv(const int* __restrict__ degi, float* __restrict__ dinv, int N) {
    int i = blockIdx.x * 256 + threadIdx.x;
    if (i < N) dinv[i] = rsqrtf((float)degi[i] + 1.0f);
}

// exclusive scan of degi -> rp (3 kernels)
__global__ void k_scan1(const int* __restrict__ degi, int* __restrict__ rp,
                        int* __restrict__ bsum, int N) {
    __shared__ int s[256];
    int t = threadIdx.x;
    int i = blockIdx.x * 256 + t;
    int v = (i < N) ? degi[i] : 0;
    s[t] = v;
    __syncthreads();
    for (int off = 1; off < 256; off <<= 1) {
        int add = (t >= off) ? s[t - off] : 0;
        __syncthreads();
        s[t] += add;
        __syncthreads();
    }
    if (i < N) rp[i] = s[t] - v;               // exclusive within block
    if (t == 255) bsum[blockIdx.x] = s[255];   // block total
}

__global__ void k_scan2(int* __restrict__ bsum, int nb) {
    __shared__ int s[512];
    int t = threadIdx.x;
    int v = (t < nb) ? bsum[t] : 0;
    s[t] = v;
    __syncthreads();
    for (int off = 1; off < 512; off <<= 1) {
        int add = (t >= off) ? s[t - off] : 0;
        __syncthreads();
        s[t] += add;
        __syncthreads();
    }
    if (t < nb) bsum[t] = s[t] - v;            // exclusive
}

__global__ void k_scan3(int* __restrict__ rp, const int* __restrict__ bsum, int N, int E) {
    int i = blockIdx.x * 256 + threadIdx.x;
    if (i < N) rp[i] += bsum[blockIdx.x];
    if (blockIdx.x == 0 && threadIdx.x == 0) rp[N] = E;
}

__global__ void k_fill(const int* __restrict__ src, const int* __restrict__ dst,
                       const int* __restrict__ rp, int* __restrict__ cnt,
                       int* __restrict__ csr_src, int E) {
    int e = blockIdx.x * 256 + threadIdx.x;
    if (e < E) {
        int d = dst[e];
        int pos = rp[d] + atomicAdd(&cnt[d], 1);
        csr_src[pos] = src[e];
    }
}

// ---- dense GEMM: Y[M,128] = X[M,128] @ W[128,128]  (fp32, no bias) --------
__global__ __launch_bounds__(256) void k_gemm128(const float* __restrict__ X,
                                                 const float* __restrict__ W,
                                                 float* __restrict__ Y, int M) {
    __shared__ float Ws[64 * 128];     // 32 KB
    __shared__ float Xs[32][129];      // 16.5 KB
    int t = threadIdx.x;
    size_t row0 = (size_t)blockIdx.x * 32;

    const float4* X4 = (const float4*)(X + row0 * 128);
#pragma unroll
    for (int i = 0; i < 4; ++i) {
        int idx = t + i * 256;
        float4 v = X4[idx];
        int r = idx >> 5, c4 = idx & 31;
        float* dp = &Xs[r][c4 * 4];
        dp[0] = v.x; dp[1] = v.y; dp[2] = v.z; dp[3] = v.w;
    }

    int cg = t & 31;
    int rg = t >> 5;
    float acc[4][4] = {{0.f}};

    const float4* W4p = (const float4*)W;
    float4* Ws4 = (float4*)Ws;
    for (int kp = 0; kp < 2; ++kp) {
        __syncthreads();
#pragma unroll
        for (int i = 0; i < 8; ++i) Ws4[t + i * 256] = W4p[kp * 2048 + t + i * 256];
        __syncthreads();
#pragma unroll 8
        for (int k = 0; k < 64; ++k) {
            float4 wv = *(const float4*)&Ws[k * 128 + cg * 4];
            int kk = kp * 64 + k;
#pragma unroll
            for (int i = 0; i < 4; ++i) {
                float xv = Xs[rg * 4 + i][kk];
                acc[i][0] += xv * wv.x;
                acc[i][1] += xv * wv.y;
                acc[i][2] += xv * wv.z;
                acc[i][3] += xv * wv.w;
            }
        }
    }
#pragma unroll
    for (int i = 0; i < 4; ++i) {
        size_t r = row0 + rg * 4 + i;
        float4 v = make_float4(acc[i][0], acc[i][1], acc[i][2], acc[i][3]);
        *(float4*)&Y[r * 128 + cg * 4] = v;
    }
}

// ---- aggregation: OUT[u] = lrelu( sum_{s in N(u)} H[s]*dinv[s]*dinv[u]
//                                   + H[u]*dinv[u]^2 + bias )
// R2: 256 threads = 8 edge-groups x 32 lanes; each lane gathers float4
// (group = one 512B row per iteration). 8x less serial depth, 2 independent
// row-gathers in flight per wave per iteration. LDS cross-group reduce.
__global__ __launch_bounds__(256) void k_agg2(const float* __restrict__ H,
                                              const int* __restrict__ csr_src,
                                              const int* __restrict__ rp,
                                              const float* __restrict__ dinv,
                                              const float* __restrict__ bias,
                                              float* __restrict__ OUT, int N) {
    __shared__ float red[8][128];      // 4 KB
    int u = blockIdx.x;
    int t = threadIdx.x;
    int g  = t >> 5;                   // edge group 0..7
    int cl = t & 31;                   // lane in group -> channels 4cl..4cl+3
    float du = dinv[u];
    int e0 = rp[u], e1 = rp[u + 1];

    float4 acc = make_float4(0.f, 0.f, 0.f, 0.f);
    for (int e = e0 + g; e < e1; e += 8) {
        int s = csr_src[e];
        float w = dinv[s] * du;
        float4 hv = *(const float4*)&H[(size_t)s * 128 + cl * 4];
        acc.x += w * hv.x; acc.y += w * hv.y;
        acc.z += w * hv.z; acc.w += w * hv.w;
    }
    *(float4*)&red[g][cl * 4] = acc;
    __syncthreads();

    if (t < 128) {
        float sum = 0.f;
#pragma unroll
        for (int i = 0; i < 8; ++i) sum += red[i][t];
        sum += H[(size_t)u * 128 + t] * (du * du) + bias[t];
        OUT[(size_t)u * 128 + t] = lrelu(sum);
    }
}

// ---- global mean pool, node-parallel --------------------------------------
#define POOL_CHUNK 256
__global__ __launch_bounds__(128) void k_pool2(const float* __restrict__ H,
                                               const int* __restrict__ batch,
                                               float* __restrict__ Gsum,
                                               int* __restrict__ Gcnt, int N) {
    int n0 = blockIdx.x * POOL_CHUNK;
    int n1 = n0 + POOL_CHUNK; if (n1 > N) n1 = N;
    if (n0 >= N) return;
    int c = threadIdx.x;
    float acc = 0.f;
    int cur = batch[n0];
    int runstart = n0;
    for (int n = n0; n < n1; ++n) {
        int g = batch[n];                      // broadcast load
        if (g != cur) {
            atomicAdd(&Gsum[cur * 128 + c], acc);
            if (c == 0) atomicAdd(&Gcnt[cur], n - runstart);
            acc = 0.f; cur = g; runstart = n;
        }
        acc += H[(size_t)n * 128 + c];
    }
    atomicAdd(&Gsum[cur * 128 + c], acc);
    if (c == 0) atomicAdd(&Gcnt[cur], n1 - runstart);
}

// ---- fused MLP head (divide-by-count folded in): one graph per block ------
__global__ __launch_bounds__(64) void k_mlp(const float* __restrict__ Gsum,
                                            const int* __restrict__ Gcnt,
                                            const float* __restrict__ W3, const float* __restrict__ b3,
                                            const float* __restrict__ W4, const float* __restrict__ b4,
                                            const float* __restrict__ W5, const float* __restrict__ b5,
                                            float* __restrict__ OUT) {
    __shared__ float row[128];
    __shared__ float t1[64];
    __shared__ float t2[64];
    int g = blockIdx.x, t = threadIdx.x;
    float inv = 1.0f / fmaxf((float)Gcnt[g], 1.0f);
    row[t]      = Gsum[g * 128 + t] * inv;
    row[t + 64] = Gsum[g * 128 + t + 64] * inv;
    __syncthreads();
    float acc = b3[t];
    for (int k = 0; k < 128; ++k) acc += row[k] * W3[k * 64 + t];
    t1[t] = lrelu(acc);
    __syncthreads();
    acc = b4[t];
    for (int k = 0; k < 64; ++k) acc += t1[k] * W4[k * 64 + t];
    t2[t] = lrelu(acc);
    __syncthreads();
    if (t < 10) {
        acc = b5[t];
        for (int k = 0; k < 64; ++k) acc += t2[k] * W5[k * 10 + t];
        OUT[g * 10 + t] = acc;
    }
}

// ---------------------------------------------------------------------------

extern "C" void kernel_launch(void* const* d_in, const int* in_sizes, int n_in,
                              void* d_out, int out_size, void* d_ws, size_t ws_size,
                              hipStream_t stream) {
    const float* x    = (const float*)d_in[0];
    const int*   ei   = (const int*)d_in[1];   // [2, E] int32
    const int*   batch= (const int*)d_in[2];
    const float* W1   = (const float*)d_in[3];
    const float* b1   = (const float*)d_in[4];
    const float* W2   = (const float*)d_in[5];
    const float* b2   = (const float*)d_in[6];
    const float* W3   = (const float*)d_in[7];
    const float* b3   = (const float*)d_in[8];
    const float* W4   = (const float*)d_in[9];
    const float* b4   = (const float*)d_in[10];
    const float* W5   = (const float*)d_in[11];
    const float* b5   = (const float*)d_in[12];
    float* out = (float*)d_out;

    const int N = in_sizes[2];          // 100000
    const int E = in_sizes[1] / 2;      // 1600000
    const int NG = 128;                 // NUM_GRAPHS

    const int* src = ei;
    const int* dst = ei + E;

    // workspace carve-up  (degi, cnt, gsum, gcnt contiguous -> one zero pass)
    char* w = (char*)d_ws;
    float* bufA = (float*)w; w += (size_t)N * 128 * 4;   // 51.2 MB
    float* bufB = (float*)w; w += (size_t)N * 128 * 4;   // 51.2 MB
    int*   degi = (int*)w;   w += (size_t)N * 4;
    int*   cnt  = (int*)w;   w += (size_t)N * 4;
    float* gsum = (float*)w; w += (size_t)NG * 128 * 4;  // 64 KB
    int*   gcnt = (int*)w;   w += (size_t)NG * 4;
    float* dinv = (float*)w; w += (size_t)N * 4;
    int*   rp   = (int*)w;   w += (size_t)(N + 8) * 4;
    int*   bsum = (int*)w;   w += 512 * 4;
    int*   csr  = (int*)w;   w += (size_t)E * 4;         // 6.4 MB
    (void)ws_size; (void)n_in; (void)out_size;

    int nbN  = (N + 255) / 256;       // 391
    int nbE  = (E + 255) / 256;       // 6250
    int nZero = 2 * N + NG * 128 + NG;
    int nbZ  = (nZero + 255) / 256;

    // CSR build + pool-accumulator zeroing (one contiguous zero pass)
    k_zero_i32<<<nbZ, 256, 0, stream>>>(degi, nZero);
    k_count<<<nbE, 256, 0, stream>>>(dst, degi, E);
    k_dinv<<<nbN, 256, 0, stream>>>(degi, dinv, N);
    k_scan1<<<nbN, 256, 0, stream>>>(degi, rp, bsum, N);
    k_scan2<<<1, 512, 0, stream>>>(bsum, nbN);
    k_scan3<<<nbN, 256, 0, stream>>>(rp, bsum, N, E);
    k_fill<<<nbE, 256, 0, stream>>>(src, dst, rp, cnt, csr, E);

    // layer 1
    k_gemm128<<<N / 32, 256, 0, stream>>>(x, W1, bufA, N);
    k_agg2<<<N, 256, 0, stream>>>(bufA, csr, rp, dinv, b1, bufB, N);
    // layer 2
    k_gemm128<<<N / 32, 256, 0, stream>>>(bufB, W2, bufA, N);
    k_agg2<<<N, 256, 0, stream>>>(bufA, csr, rp, dinv, b2, bufB, N);

    // pool + MLP head
    int nbP = (N + POOL_CHUNK - 1) / POOL_CHUNK;
    k_pool2<<<nbP, 128, 0, stream>>>(bufB, batch, gsum, gcnt, N);
    k_mlp<<<NG, 64, 0, stream>>>(gsum, gcnt, W3, b3, W4, b4, W5, b5, out);
}

// Round 4
// 625.570 us; speedup vs baseline: 1.5198x; 1.1755x over previous
//
#include <hip/hip_runtime.h>
#include <hip/hip_bf16.h>

// ---------------------------------------------------------------------------
// GCN: h1 = lrelu(GCNConv(x; W1,b1)); h2 = lrelu(GCNConv(h1; W2,b2));
//      g = segment_mean(h2, batch); MLP head W3/W4/W5.
// R1: node-parallel pooling (213us -> ~15us).
// R2: k_agg 8-way edge-parallel float4 gathers (183 -> 141us @3.4TB/s).
// R3: H matrix in bf16 -> gather bytes halve (agg ~75us) and GEMMs move to
//     MFMA 16x16x32_bf16 with fp32 accumulate (~115us -> ~10us each).
//     All accumulation fp32; bf16 is storage + MFMA input only.
// ---------------------------------------------------------------------------

#define SLOPE 0.01f

__device__ __forceinline__ float lrelu(float x) { return x > 0.f ? x : SLOPE * x; }

// bf16 helpers (RNE round, bit-shift expand)
__device__ __forceinline__ unsigned short f2bf(float f) {
    union { float f; unsigned u; } v; v.f = f;
    unsigned r = v.u + 0x7fffu + ((v.u >> 16) & 1u);
    return (unsigned short)(r >> 16);
}
__device__ __forceinline__ float bf2f(unsigned short h) {
    union { unsigned u; float f; } v; v.u = ((unsigned)h) << 16;
    return v.f;
}
__device__ __forceinline__ float bf_lo(unsigned x) {
    union { unsigned u; float f; } v; v.u = x << 16; return v.f;
}
__device__ __forceinline__ float bf_hi(unsigned x) {
    union { unsigned u; float f; } v; v.u = x & 0xffff0000u; return v.f;
}

typedef __attribute__((ext_vector_type(8))) short bf16x8;
typedef __attribute__((ext_vector_type(4))) float f32x4;

// ---- setup kernels --------------------------------------------------------

__global__ void k_zero_i32(int* __restrict__ a, int n) {
    int i = blockIdx.x * 256 + threadIdx.x;
    if (i < n) a[i] = 0;
}

__global__ void k_count(const int* __restrict__ dst, int* __restrict__ degi, int E) {
    int e = blockIdx.x * 256 + threadIdx.x;
    if (e < E) atomicAdd(&degi[dst[e]], 1);
}

__global__ void k_dinv(const int* __restrict__ degi, float* __restrict__ dinv, int N) {
    int i = blockIdx.x * 256 + threadIdx.x;
    if (i < N) dinv[i] = rsqrtf((float)degi[i] + 1.0f);
}

// exclusive scan of degi -> rp (3 kernels)
__global__ void k_scan1(const int* __restrict__ degi, int* __restrict__ rp,
                        int* __restrict__ bsum, int N) {
    __shared__ int s[256];
    int t = threadIdx.x;
    int i = blockIdx.x * 256 + t;
    int v = (i < N) ? degi[i] : 0;
    s[t] = v;
    __syncthreads();
    for (int off = 1; off < 256; off <<= 1) {
        int add = (t >= off) ? s[t - off] : 0;
        __syncthreads();
        s[t] += add;
        __syncthreads();
    }
    if (i < N) rp[i] = s[t] - v;
    if (t == 255) bsum[blockIdx.x] = s[255];
}

__global__ void k_scan2(int* __restrict__ bsum, int nb) {
    __shared__ int s[512];
    int t = threadIdx.x;
    int v = (t < nb) ? bsum[t] : 0;
    s[t] = v;
    __syncthreads();
    for (int off = 1; off < 512; off <<= 1) {
        int add = (t >= off) ? s[t - off] : 0;
        __syncthreads();
        s[t] += add;
        __syncthreads();
    }
    if (t < nb) bsum[t] = s[t] - v;
}

__global__ void k_scan3(int* __restrict__ rp, const int* __restrict__ bsum, int N, int E) {
    int i = blockIdx.x * 256 + threadIdx.x;
    if (i < N) rp[i] += bsum[blockIdx.x];
    if (blockIdx.x == 0 && threadIdx.x == 0) rp[N] = E;
}

__global__ void k_fill(const int* __restrict__ src, const int* __restrict__ dst,
                       const int* __restrict__ rp, int* __restrict__ cnt,
                       int* __restrict__ csr_src, int E) {
    int e = blockIdx.x * 256 + threadIdx.x;
    if (e < E) {
        int d = dst[e];
        int pos = rp[d] + atomicAdd(&cnt[d], 1);
        csr_src[pos] = src[e];
    }
}

// ---- MFMA GEMM: Y[M,128](bf16) = X[M,128] @ W[128,128](fp32->bf16) --------
// 64-row block tile, 4 waves x (16 rows x 128 cols), K=128 in 4 chunks of 32.
// W transposed into LDS once per block so B-fragments are contiguous b128.
#define LDA 136   // row pad +8 bf16: 2-way LDS aliasing only (free per m136)

template<bool IN_BF16>
__global__ __launch_bounds__(256) void k_gemm_mfma(const void* __restrict__ Xv,
                                                   const float* __restrict__ W,
                                                   unsigned short* __restrict__ Y,
                                                   int M) {
    __shared__ unsigned short As[64 * LDA];    // 17.4 KB
    __shared__ unsigned short Bs[128 * LDA];   // 34.8 KB, Bs[n][k] = W[k][n]
    int t = threadIdx.x;
    int row0 = blockIdx.x * 64;

    // stage W^T (16384 elems, coalesced read, scattered LDS write; once/block)
#pragma unroll
    for (int i = 0; i < 64; ++i) {
        int idx = t + i * 256;
        int k = idx >> 7, n = idx & 127;
        Bs[n * LDA + k] = f2bf(W[idx]);
    }
    // stage A rows (convert fp32->bf16 if needed), zero-pad past M
    if (IN_BF16) {
        const uint4* X4 = (const uint4*)Xv;
#pragma unroll
        for (int i = 0; i < 4; ++i) {
            int idx = t + i * 256;          // 16 uint4 per row
            int r = idx >> 4, c8 = idx & 15;
            int gr = row0 + r;
            uint4 v = (gr < M) ? X4[(size_t)gr * 16 + c8] : make_uint4(0, 0, 0, 0);
            *(uint4*)&As[r * LDA + c8 * 8] = v;
        }
    } else {
        const float4* X4 = (const float4*)Xv;
#pragma unroll
        for (int i = 0; i < 8; ++i) {
            int idx = t + i * 256;          // 32 float4 per row
            int r = idx >> 5, c4 = idx & 31;
            int gr = row0 + r;
            float4 v = (gr < M) ? X4[(size_t)gr * 32 + c4] : make_float4(0.f, 0.f, 0.f, 0.f);
            ushort2 p0 = make_ushort2(f2bf(v.x), f2bf(v.y));
            ushort2 p1 = make_ushort2(f2bf(v.z), f2bf(v.w));
            *(ushort2*)&As[r * LDA + c4 * 4]     = p0;
            *(ushort2*)&As[r * LDA + c4 * 4 + 2] = p1;
        }
    }
    __syncthreads();

    int w = t >> 6, l = t & 63;
    int lr = l & 15;              // row-in-tile (A) / col-in-tile (B,D)
    int ko = (l >> 4) * 8;        // k offset of this quad

    f32x4 acc[8];
#pragma unroll
    for (int c = 0; c < 8; ++c) acc[c] = (f32x4){0.f, 0.f, 0.f, 0.f};

#pragma unroll
    for (int kc = 0; kc < 4; ++kc) {
        int kb = kc * 32 + ko;
        bf16x8 af = *(const bf16x8*)&As[(w * 16 + lr) * LDA + kb];
        bf16x8 bfr[8];
#pragma unroll
        for (int ct = 0; ct < 8; ++ct)
            bfr[ct] = *(const bf16x8*)&Bs[(ct * 16 + lr) * LDA + kb];
#pragma unroll
        for (int ct = 0; ct < 8; ++ct)
            acc[ct] = __builtin_amdgcn_mfma_f32_16x16x32_bf16(af, bfr[ct], acc[ct], 0, 0, 0);
    }

    // D layout: col = l&15, row = (l>>4)*4 + i   [m89/m91 verified]
    int qr = (l >> 4) * 4;
#pragma unroll
    for (int i = 0; i < 4; ++i) {
        int gr = row0 + w * 16 + qr + i;
        if (gr < M) {
#pragma unroll
            for (int ct = 0; ct < 8; ++ct)
                Y[(size_t)gr * 128 + ct * 16 + lr] = f2bf(acc[ct][i]);
        }
    }
}

// ---- aggregation (bf16 H): OUT[u] = lrelu( sum w*H[s] + H[u]/deg + b ) ----
// 256 threads = 16 edge-groups x 16 lanes; lane gathers 16B (8 bf16 ch).
// One group covers a full 256B row per iteration; fp32 accumulate.
__global__ __launch_bounds__(256) void k_agg3(const unsigned short* __restrict__ H,
                                              const int* __restrict__ csr_src,
                                              const int* __restrict__ rp,
                                              const float* __restrict__ dinv,
                                              const float* __restrict__ bias,
                                              unsigned short* __restrict__ OUT, int N) {
    __shared__ float red[16][128];     // 8 KB
    int u = blockIdx.x, t = threadIdx.x;
    int g = t >> 4, cl = t & 15;
    float du = dinv[u];
    int e0 = rp[u], e1 = rp[u + 1];

    float acc[8] = {0.f, 0.f, 0.f, 0.f, 0.f, 0.f, 0.f, 0.f};
    for (int e = e0 + g; e < e1; e += 16) {
        int s = csr_src[e];
        float w = dinv[s] * du;
        uint4 hv = *(const uint4*)&H[(size_t)s * 128 + cl * 8];
        acc[0] += w * bf_lo(hv.x); acc[1] += w * bf_hi(hv.x);
        acc[2] += w * bf_lo(hv.y); acc[3] += w * bf_hi(hv.y);
        acc[4] += w * bf_lo(hv.z); acc[5] += w * bf_hi(hv.z);
        acc[6] += w * bf_lo(hv.w); acc[7] += w * bf_hi(hv.w);
    }
#pragma unroll
    for (int j = 0; j < 8; ++j) red[g][cl * 8 + j] = acc[j];
    __syncthreads();

    if (t < 128) {
        float sum = 0.f;
#pragma unroll
        for (int i = 0; i < 16; ++i) sum += red[i][t];
        sum += bf2f(H[(size_t)u * 128 + t]) * (du * du) + bias[t];
        OUT[(size_t)u * 128 + t] = f2bf(lrelu(sum));
    }
}

// ---- global mean pool, node-parallel (bf16 input, fp32 accum) -------------
#define POOL_CHUNK 256
__global__ __launch_bounds__(128) void k_pool2(const unsigned short* __restrict__ H,
                                               const int* __restrict__ batch,
                                               float* __restrict__ Gsum,
                                               int* __restrict__ Gcnt, int N) {
    int n0 = blockIdx.x * POOL_CHUNK;
    int n1 = n0 + POOL_CHUNK; if (n1 > N) n1 = N;
    if (n0 >= N) return;
    int c = threadIdx.x;
    float acc = 0.f;
    int cur = batch[n0];
    int runstart = n0;
    for (int n = n0; n < n1; ++n) {
        int g = batch[n];
        if (g != cur) {
            atomicAdd(&Gsum[cur * 128 + c], acc);
            if (c == 0) atomicAdd(&Gcnt[cur], n - runstart);
            acc = 0.f; cur = g; runstart = n;
        }
        acc += bf2f(H[(size_t)n * 128 + c]);
    }
    atomicAdd(&Gsum[cur * 128 + c], acc);
    if (c == 0) atomicAdd(&Gcnt[cur], n1 - runstart);
}

// ---- fused MLP head (divide-by-count folded in): one graph per block ------
__global__ __launch_bounds__(64) void k_mlp(const float* __restrict__ Gsum,
                                            const int* __restrict__ Gcnt,
                                            const float* __restrict__ W3, const float* __restrict__ b3,
                                            const float* __restrict__ W4, const float* __restrict__ b4,
                                            const float* __restrict__ W5, const float* __restrict__ b5,
                                            float* __restrict__ OUT) {
    __shared__ float row[128];
    __shared__ float t1[64];
    __shared__ float t2[64];
    int g = blockIdx.x, t = threadIdx.x;
    float inv = 1.0f / fmaxf((float)Gcnt[g], 1.0f);
    row[t]      = Gsum[g * 128 + t] * inv;
    row[t + 64] = Gsum[g * 128 + t + 64] * inv;
    __syncthreads();
    float acc = b3[t];
    for (int k = 0; k < 128; ++k) acc += row[k] * W3[k * 64 + t];
    t1[t] = lrelu(acc);
    __syncthreads();
    acc = b4[t];
    for (int k = 0; k < 64; ++k) acc += t1[k] * W4[k * 64 + t];
    t2[t] = lrelu(acc);
    __syncthreads();
    if (t < 10) {
        acc = b5[t];
        for (int k = 0; k < 64; ++k) acc += t2[k] * W5[k * 10 + t];
        OUT[g * 10 + t] = acc;
    }
}

// ---------------------------------------------------------------------------

extern "C" void kernel_launch(void* const* d_in, const int* in_sizes, int n_in,
                              void* d_out, int out_size, void* d_ws, size_t ws_size,
                              hipStream_t stream) {
    const float* x    = (const float*)d_in[0];
    const int*   ei   = (const int*)d_in[1];   // [2, E] int32
    const int*   batch= (const int*)d_in[2];
    const float* W1   = (const float*)d_in[3];
    const float* b1   = (const float*)d_in[4];
    const float* W2   = (const float*)d_in[5];
    const float* b2   = (const float*)d_in[6];
    const float* W3   = (const float*)d_in[7];
    const float* b3   = (const float*)d_in[8];
    const float* W4   = (const float*)d_in[9];
    const float* b4   = (const float*)d_in[10];
    const float* W5   = (const float*)d_in[11];
    const float* b5   = (const float*)d_in[12];
    float* out = (float*)d_out;

    const int N = in_sizes[2];          // 100000
    const int E = in_sizes[1] / 2;      // 1600000
    const int NG = 128;                 // NUM_GRAPHS

    const int* src = ei;
    const int* dst = ei + E;

    // workspace carve-up  (degi, cnt, gsum, gcnt contiguous -> one zero pass)
    char* w = (char*)d_ws;
    unsigned short* bufA = (unsigned short*)w; w += (size_t)N * 128 * 2;  // 25.6 MB
    unsigned short* bufB = (unsigned short*)w; w += (size_t)N * 128 * 2;  // 25.6 MB
    int*   degi = (int*)w;   w += (size_t)N * 4;
    int*   cnt  = (int*)w;   w += (size_t)N * 4;
    float* gsum = (float*)w; w += (size_t)NG * 128 * 4;
    int*   gcnt = (int*)w;   w += (size_t)NG * 4;
    float* dinv = (float*)w; w += (size_t)N * 4;
    int*   rp   = (int*)w;   w += (size_t)(N + 8) * 4;
    int*   bsum = (int*)w;   w += 512 * 4;
    int*   csr  = (int*)w;   w += (size_t)E * 4;         // 6.4 MB
    (void)ws_size; (void)n_in; (void)out_size;

    int nbN  = (N + 255) / 256;       // 391
    int nbE  = (E + 255) / 256;       // 6250
    int nZero = 2 * N + NG * 128 + NG;
    int nbZ  = (nZero + 255) / 256;

    // CSR build + pool-accumulator zeroing (one contiguous zero pass)
    k_zero_i32<<<nbZ, 256, 0, stream>>>(degi, nZero);
    k_count<<<nbE, 256, 0, stream>>>(dst, degi, E);
    k_dinv<<<nbN, 256, 0, stream>>>(degi, dinv, N);
    k_scan1<<<nbN, 256, 0, stream>>>(degi, rp, bsum, N);
    k_scan2<<<1, 512, 0, stream>>>(bsum, nbN);
    k_scan3<<<nbN, 256, 0, stream>>>(rp, bsum, N, E);
    k_fill<<<nbE, 256, 0, stream>>>(src, dst, rp, cnt, csr, E);

    int nbG = (N + 63) / 64;          // 1563 GEMM blocks

    // layer 1
    k_gemm_mfma<false><<<nbG, 256, 0, stream>>>(x, W1, bufA, N);
    k_agg3<<<N, 256, 0, stream>>>(bufA, csr, rp, dinv, b1, bufB, N);
    // layer 2
    k_gemm_mfma<true><<<nbG, 256, 0, stream>>>(bufB, W2, bufA, N);
    k_agg3<<<N, 256, 0, stream>>>(bufA, csr, rp, dinv, b2, bufB, N);

    // pool + MLP head
    int nbP = (N + POOL_CHUNK - 1) / POOL_CHUNK;
    k_pool2<<<nbP, 128, 0, stream>>>(bufB, batch, gsum, gcnt, N);
    k_mlp<<<NG, 64, 0, stream>>>(gsum, gcnt, W3, b3, W4, b4, W5, b5, out);
}

// Round 5
// 559.776 us; speedup vs baseline: 1.6984x; 1.1175x over previous
//
#include <hip/hip_runtime.h>
#include <hip/hip_bf16.h>

// ---------------------------------------------------------------------------
// GCN: h1 = lrelu(GCNConv(x; W1,b1)); h2 = lrelu(GCNConv(h1; W2,b2));
//      g = segment_mean(h2, batch); MLP head W3/W4/W5.
// R1: node-parallel pooling (213us -> ~15us).
// R2: k_agg 8-way edge-parallel float4 gathers (183 -> 141us @3.4TB/s).
// R3: bf16 H: agg bytes halve; GEMMs -> MFMA 16x16x32_bf16 (625us total).
// R4: CSR fill without atomics: k_count stores its atomicAdd return as the
//     in-bucket position (coalesced); k_fill = pure scatter store. 4 edges/
//     thread int4 ILP. dinv folded into scan1.
// ---------------------------------------------------------------------------

#define SLOPE 0.01f

__device__ __forceinline__ float lrelu(float x) { return x > 0.f ? x : SLOPE * x; }

// bf16 helpers (RNE round, bit-shift expand)
__device__ __forceinline__ unsigned short f2bf(float f) {
    union { float f; unsigned u; } v; v.f = f;
    unsigned r = v.u + 0x7fffu + ((v.u >> 16) & 1u);
    return (unsigned short)(r >> 16);
}
__device__ __forceinline__ float bf2f(unsigned short h) {
    union { unsigned u; float f; } v; v.u = ((unsigned)h) << 16;
    return v.f;
}
__device__ __forceinline__ float bf_lo(unsigned x) {
    union { unsigned u; float f; } v; v.u = x << 16; return v.f;
}
__device__ __forceinline__ float bf_hi(unsigned x) {
    union { unsigned u; float f; } v; v.u = x & 0xffff0000u; return v.f;
}

typedef __attribute__((ext_vector_type(8))) short bf16x8;
typedef __attribute__((ext_vector_type(4))) float f32x4;

// ---- setup kernels --------------------------------------------------------

__global__ void k_zero_i32(int* __restrict__ a, int n) {
    int i = blockIdx.x * 256 + threadIdx.x;
    if (i < n) a[i] = 0;
}

// count + record per-edge position (atomicAdd return). 4 edges/thread.
__global__ void k_count4(const int* __restrict__ dst, int* __restrict__ degi,
                         int* __restrict__ pos, int E) {
    int i = blockIdx.x * 256 + threadIdx.x;
    int e = i * 4;
    if (e + 3 < E) {
        int4 d = *(const int4*)&dst[e];
        int4 p;
        p.x = atomicAdd(&degi[d.x], 1);
        p.y = atomicAdd(&degi[d.y], 1);
        p.z = atomicAdd(&degi[d.z], 1);
        p.w = atomicAdd(&degi[d.w], 1);
        *(int4*)&pos[e] = p;
    } else {
        for (; e < E; ++e) pos[e] = atomicAdd(&degi[dst[e]], 1);
    }
}

// atomic-free scatter fill: csr[rp[dst]+pos] = src. 4 edges/thread.
__global__ void k_fill4(const int* __restrict__ src, const int* __restrict__ dst,
                        const int* __restrict__ pos, const int* __restrict__ rp,
                        int* __restrict__ csr_src, int E) {
    int i = blockIdx.x * 256 + threadIdx.x;
    int e = i * 4;
    if (e + 3 < E) {
        int4 s = *(const int4*)&src[e];
        int4 d = *(const int4*)&dst[e];
        int4 p = *(const int4*)&pos[e];
        csr_src[rp[d.x] + p.x] = s.x;
        csr_src[rp[d.y] + p.y] = s.y;
        csr_src[rp[d.z] + p.z] = s.z;
        csr_src[rp[d.w] + p.w] = s.w;
    } else {
        for (; e < E; ++e) csr_src[rp[dst[e]] + pos[e]] = src[e];
    }
}

// exclusive scan of degi -> rp (3 kernels); dinv folded into pass 1
__global__ void k_scan1(const int* __restrict__ degi, int* __restrict__ rp,
                        int* __restrict__ bsum, float* __restrict__ dinv, int N) {
    __shared__ int s[256];
    int t = threadIdx.x;
    int i = blockIdx.x * 256 + t;
    int v = (i < N) ? degi[i] : 0;
    s[t] = v;
    __syncthreads();
    for (int off = 1; off < 256; off <<= 1) {
        int add = (t >= off) ? s[t - off] : 0;
        __syncthreads();
        s[t] += add;
        __syncthreads();
    }
    if (i < N) {
        rp[i] = s[t] - v;
        dinv[i] = rsqrtf((float)v + 1.0f);
    }
    if (t == 255) bsum[blockIdx.x] = s[255];
}

__global__ void k_scan2(int* __restrict__ bsum, int nb) {
    __shared__ int s[512];
    int t = threadIdx.x;
    int v = (t < nb) ? bsum[t] : 0;
    s[t] = v;
    __syncthreads();
    for (int off = 1; off < 512; off <<= 1) {
        int add = (t >= off) ? s[t - off] : 0;
        __syncthreads();
        s[t] += add;
        __syncthreads();
    }
    if (t < nb) bsum[t] = s[t] - v;
}

__global__ void k_scan3(int* __restrict__ rp, const int* __restrict__ bsum, int N, int E) {
    int i = blockIdx.x * 256 + threadIdx.x;
    if (i < N) rp[i] += bsum[blockIdx.x];
    if (blockIdx.x == 0 && threadIdx.x == 0) rp[N] = E;
}

// ---- MFMA GEMM: Y[M,128](bf16) = X[M,128] @ W[128,128](fp32->bf16) --------
#define LDA 136   // row pad +8 bf16: 2-way LDS aliasing only (free per m136)

template<bool IN_BF16>
__global__ __launch_bounds__(256) void k_gemm_mfma(const void* __restrict__ Xv,
                                                   const float* __restrict__ W,
                                                   unsigned short* __restrict__ Y,
                                                   int M) {
    __shared__ unsigned short As[64 * LDA];    // 17.4 KB
    __shared__ unsigned short Bs[128 * LDA];   // 34.8 KB, Bs[n][k] = W[k][n]
    int t = threadIdx.x;
    int row0 = blockIdx.x * 64;

#pragma unroll
    for (int i = 0; i < 64; ++i) {
        int idx = t + i * 256;
        int k = idx >> 7, n = idx & 127;
        Bs[n * LDA + k] = f2bf(W[idx]);
    }
    if (IN_BF16) {
        const uint4* X4 = (const uint4*)Xv;
#pragma unroll
        for (int i = 0; i < 4; ++i) {
            int idx = t + i * 256;
            int r = idx >> 4, c8 = idx & 15;
            int gr = row0 + r;
            uint4 v = (gr < M) ? X4[(size_t)gr * 16 + c8] : make_uint4(0, 0, 0, 0);
            *(uint4*)&As[r * LDA + c8 * 8] = v;
        }
    } else {
        const float4* X4 = (const float4*)Xv;
#pragma unroll
        for (int i = 0; i < 8; ++i) {
            int idx = t + i * 256;
            int r = idx >> 5, c4 = idx & 31;
            int gr = row0 + r;
            float4 v = (gr < M) ? X4[(size_t)gr * 32 + c4] : make_float4(0.f, 0.f, 0.f, 0.f);
            ushort2 p0 = make_ushort2(f2bf(v.x), f2bf(v.y));
            ushort2 p1 = make_ushort2(f2bf(v.z), f2bf(v.w));
            *(ushort2*)&As[r * LDA + c4 * 4]     = p0;
            *(ushort2*)&As[r * LDA + c4 * 4 + 2] = p1;
        }
    }
    __syncthreads();

    int w = t >> 6, l = t & 63;
    int lr = l & 15;
    int ko = (l >> 4) * 8;

    f32x4 acc[8];
#pragma unroll
    for (int c = 0; c < 8; ++c) acc[c] = (f32x4){0.f, 0.f, 0.f, 0.f};

#pragma unroll
    for (int kc = 0; kc < 4; ++kc) {
        int kb = kc * 32 + ko;
        bf16x8 af = *(const bf16x8*)&As[(w * 16 + lr) * LDA + kb];
        bf16x8 bfr[8];
#pragma unroll
        for (int ct = 0; ct < 8; ++ct)
            bfr[ct] = *(const bf16x8*)&Bs[(ct * 16 + lr) * LDA + kb];
#pragma unroll
        for (int ct = 0; ct < 8; ++ct)
            acc[ct] = __builtin_amdgcn_mfma_f32_16x16x32_bf16(af, bfr[ct], acc[ct], 0, 0, 0);
    }

    int qr = (l >> 4) * 4;
#pragma unroll
    for (int i = 0; i < 4; ++i) {
        int gr = row0 + w * 16 + qr + i;
        if (gr < M) {
#pragma unroll
            for (int ct = 0; ct < 8; ++ct)
                Y[(size_t)gr * 128 + ct * 16 + lr] = f2bf(acc[ct][i]);
        }
    }
}

// ---- aggregation (bf16 H): OUT[u] = lrelu( sum w*H[s] + H[u]/deg + b ) ----
__global__ __launch_bounds__(256) void k_agg3(const unsigned short* __restrict__ H,
                                              const int* __restrict__ csr_src,
                                              const int* __restrict__ rp,
                                              const float* __restrict__ dinv,
                                              const float* __restrict__ bias,
                                              unsigned short* __restrict__ OUT, int N) {
    __shared__ float red[16][128];     // 8 KB
    int u = blockIdx.x, t = threadIdx.x;
    int g = t >> 4, cl = t & 15;
    float du = dinv[u];
    int e0 = rp[u], e1 = rp[u + 1];

    float acc[8] = {0.f, 0.f, 0.f, 0.f, 0.f, 0.f, 0.f, 0.f};
    for (int e = e0 + g; e < e1; e += 16) {
        int s = csr_src[e];
        float w = dinv[s] * du;
        uint4 hv = *(const uint4*)&H[(size_t)s * 128 + cl * 8];
        acc[0] += w * bf_lo(hv.x); acc[1] += w * bf_hi(hv.x);
        acc[2] += w * bf_lo(hv.y); acc[3] += w * bf_hi(hv.y);
        acc[4] += w * bf_lo(hv.z); acc[5] += w * bf_hi(hv.z);
        acc[6] += w * bf_lo(hv.w); acc[7] += w * bf_hi(hv.w);
    }
#pragma unroll
    for (int j = 0; j < 8; ++j) red[g][cl * 8 + j] = acc[j];
    __syncthreads();

    if (t < 128) {
        float sum = 0.f;
#pragma unroll
        for (int i = 0; i < 16; ++i) sum += red[i][t];
        sum += bf2f(H[(size_t)u * 128 + t]) * (du * du) + bias[t];
        OUT[(size_t)u * 128 + t] = f2bf(lrelu(sum));
    }
}

// ---- global mean pool, node-parallel (bf16 input, fp32 accum) -------------
#define POOL_CHUNK 256
__global__ __launch_bounds__(128) void k_pool2(const unsigned short* __restrict__ H,
                                               const int* __restrict__ batch,
                                               float* __restrict__ Gsum,
                                               int* __restrict__ Gcnt, int N) {
    int n0 = blockIdx.x * POOL_CHUNK;
    int n1 = n0 + POOL_CHUNK; if (n1 > N) n1 = N;
    if (n0 >= N) return;
    int c = threadIdx.x;
    float acc = 0.f;
    int cur = batch[n0];
    int runstart = n0;
    for (int n = n0; n < n1; ++n) {
        int g = batch[n];
        if (g != cur) {
            atomicAdd(&Gsum[cur * 128 + c], acc);
            if (c == 0) atomicAdd(&Gcnt[cur], n - runstart);
            acc = 0.f; cur = g; runstart = n;
        }
        acc += bf2f(H[(size_t)n * 128 + c]);
    }
    atomicAdd(&Gsum[cur * 128 + c], acc);
    if (c == 0) atomicAdd(&Gcnt[cur], n1 - runstart);
}

// ---- fused MLP head (divide-by-count folded in): one graph per block ------
__global__ __launch_bounds__(64) void k_mlp(const float* __restrict__ Gsum,
                                            const int* __restrict__ Gcnt,
                                            const float* __restrict__ W3, const float* __restrict__ b3,
                                            const float* __restrict__ W4, const float* __restrict__ b4,
                                            const float* __restrict__ W5, const float* __restrict__ b5,
                                            float* __restrict__ OUT) {
    __shared__ float row[128];
    __shared__ float t1[64];
    __shared__ float t2[64];
    int g = blockIdx.x, t = threadIdx.x;
    float inv = 1.0f / fmaxf((float)Gcnt[g], 1.0f);
    row[t]      = Gsum[g * 128 + t] * inv;
    row[t + 64] = Gsum[g * 128 + t + 64] * inv;
    __syncthreads();
    float acc = b3[t];
    for (int k = 0; k < 128; ++k) acc += row[k] * W3[k * 64 + t];
    t1[t] = lrelu(acc);
    __syncthreads();
    acc = b4[t];
    for (int k = 0; k < 64; ++k) acc += t1[k] * W4[k * 64 + t];
    t2[t] = lrelu(acc);
    __syncthreads();
    if (t < 10) {
        acc = b5[t];
        for (int k = 0; k < 64; ++k) acc += t2[k] * W5[k * 10 + t];
        OUT[g * 10 + t] = acc;
    }
}

// ---------------------------------------------------------------------------

extern "C" void kernel_launch(void* const* d_in, const int* in_sizes, int n_in,
                              void* d_out, int out_size, void* d_ws, size_t ws_size,
                              hipStream_t stream) {
    const float* x    = (const float*)d_in[0];
    const int*   ei   = (const int*)d_in[1];   // [2, E] int32
    const int*   batch= (const int*)d_in[2];
    const float* W1   = (const float*)d_in[3];
    const float* b1   = (const float*)d_in[4];
    const float* W2   = (const float*)d_in[5];
    const float* b2   = (const float*)d_in[6];
    const float* W3   = (const float*)d_in[7];
    const float* b3   = (const float*)d_in[8];
    const float* W4   = (const float*)d_in[9];
    const float* b4   = (const float*)d_in[10];
    const float* W5   = (const float*)d_in[11];
    const float* b5   = (const float*)d_in[12];
    float* out = (float*)d_out;

    const int N = in_sizes[2];          // 100000
    const int E = in_sizes[1] / 2;      // 1600000
    const int NG = 128;                 // NUM_GRAPHS

    const int* src = ei;
    const int* dst = ei + E;

    // workspace carve-up  (degi, gsum, gcnt contiguous -> one zero pass)
    char* w = (char*)d_ws;
    unsigned short* bufA = (unsigned short*)w; w += (size_t)N * 128 * 2;  // 25.6 MB
    unsigned short* bufB = (unsigned short*)w; w += (size_t)N * 128 * 2;  // 25.6 MB
    int*   degi = (int*)w;   w += (size_t)N * 4;
    float* gsum = (float*)w; w += (size_t)NG * 128 * 4;
    int*   gcnt = (int*)w;   w += (size_t)NG * 4;
    float* dinv = (float*)w; w += (size_t)N * 4;
    int*   rp   = (int*)w;   w += (size_t)(N + 8) * 4;
    int*   bsum = (int*)w;   w += 512 * 4;
    int*   csr  = (int*)w;   w += (size_t)E * 4;         // 6.4 MB
    int*   pos  = (int*)w;   w += (size_t)E * 4;         // 6.4 MB
    (void)ws_size; (void)n_in; (void)out_size;

    int nbN  = (N + 255) / 256;       // 391
    int nbE4 = (E / 4 + 255) / 256;   // 1563
    int nZero = N + NG * 128 + NG;
    int nbZ  = (nZero + 255) / 256;

    // CSR build + pool-accumulator zeroing
    k_zero_i32<<<nbZ, 256, 0, stream>>>(degi, nZero);
    k_count4<<<nbE4, 256, 0, stream>>>(dst, degi, pos, E);
    k_scan1<<<nbN, 256, 0, stream>>>(degi, rp, bsum, dinv, N);
    k_scan2<<<1, 512, 0, stream>>>(bsum, nbN);
    k_scan3<<<nbN, 256, 0, stream>>>(rp, bsum, N, E);
    k_fill4<<<nbE4, 256, 0, stream>>>(src, dst, pos, rp, csr, E);

    int nbG = (N + 63) / 64;          // 1563 GEMM blocks

    // layer 1
    k_gemm_mfma<false><<<nbG, 256, 0, stream>>>(x, W1, bufA, N);
    k_agg3<<<N, 256, 0, stream>>>(bufA, csr, rp, dinv, b1, bufB, N);
    // layer 2
    k_gemm_mfma<true><<<nbG, 256, 0, stream>>>(bufB, W2, bufA, N);
    k_agg3<<<N, 256, 0, stream>>>(bufA, csr, rp, dinv, b2, bufB, N);

    // pool + MLP head
    int nbP = (N + POOL_CHUNK - 1) / POOL_CHUNK;
    k_pool2<<<nbP, 128, 0, stream>>>(bufB, batch, gsum, gcnt, N);
    k_mlp<<<NG, 64, 0, stream>>>(gsum, gcnt, W3, b3, W4, b4, W5, b5, out);
}

// Round 6
// 475.135 us; speedup vs baseline: 2.0010x; 1.1781x over previous
//
#include <hip/hip_runtime.h>
#include <hip/hip_bf16.h>

// ---------------------------------------------------------------------------
// GCN: h1 = lrelu(GCNConv(x; W1,b1)); h2 = lrelu(GCNConv(h1; W2,b2));
//      g = segment_mean(h2, batch); MLP head W3/W4/W5.
// R1: node-parallel pooling (213us -> ~15us).
// R2: k_agg 8-way edge-parallel float4 gathers (183 -> 141us).
// R3: bf16 H; GEMMs -> MFMA 16x16x32_bf16.
// R4: atomic-free CSR fill (pos from count's atomicAdd return).
// R5: k_agg4 wave-per-node, no LDS/barrier (6.4M bank conflicts -> 0),
//     self-loop folded into CSR, per-edge weight precomputed in fill;
//     GEMM: W^T prepacked bf16 once per layer + LDS-repacked uint4 stores.
// ---------------------------------------------------------------------------

#define SLOPE 0.01f

__device__ __forceinline__ float lrelu(float x) { return x > 0.f ? x : SLOPE * x; }

// bf16 helpers (RNE round, bit-shift expand)
__device__ __forceinline__ unsigned short f2bf(float f) {
    union { float f; unsigned u; } v; v.f = f;
    unsigned r = v.u + 0x7fffu + ((v.u >> 16) & 1u);
    return (unsigned short)(r >> 16);
}
__device__ __forceinline__ float bf2f(unsigned short h) {
    union { unsigned u; float f; } v; v.u = ((unsigned)h) << 16;
    return v.f;
}
__device__ __forceinline__ float bf_lo(unsigned x) {
    union { unsigned u; float f; } v; v.u = x << 16; return v.f;
}
__device__ __forceinline__ float bf_hi(unsigned x) {
    union { unsigned u; float f; } v; v.u = x & 0xffff0000u; return v.f;
}
__device__ __forceinline__ unsigned packbf(float lo, float hi) {
    return (unsigned)f2bf(lo) | ((unsigned)f2bf(hi) << 16);
}

typedef __attribute__((ext_vector_type(8))) short bf16x8;
typedef __attribute__((ext_vector_type(4))) float f32x4;

// ---- setup kernels --------------------------------------------------------

__global__ void k_zero_i32(int* __restrict__ a, int n) {
    int i = blockIdx.x * 256 + threadIdx.x;
    if (i < n) a[i] = 0;
}

// count + record per-edge position (atomicAdd return). 4 edges/thread.
__global__ void k_count4(const int* __restrict__ dst, int* __restrict__ degi,
                         int* __restrict__ pos, int E) {
    int i = blockIdx.x * 256 + threadIdx.x;
    int e = i * 4;
    if (e + 3 < E) {
        int4 d = *(const int4*)&dst[e];
        int4 p;
        p.x = atomicAdd(&degi[d.x], 1);
        p.y = atomicAdd(&degi[d.y], 1);
        p.z = atomicAdd(&degi[d.z], 1);
        p.w = atomicAdd(&degi[d.w], 1);
        *(int4*)&pos[e] = p;
    } else {
        for (; e < E; ++e) pos[e] = atomicAdd(&degi[dst[e]], 1);
    }
}

// exclusive scan of (degi+1) -> rp  (+1 = self-loop slot); dinv folded in
__global__ void k_scan1(const int* __restrict__ degi, int* __restrict__ rp,
                        int* __restrict__ bsum, float* __restrict__ dinv, int N) {
    __shared__ int s[256];
    int t = threadIdx.x;
    int i = blockIdx.x * 256 + t;
    int v = (i < N) ? (degi[i] + 1) : 0;
    s[t] = v;
    __syncthreads();
    for (int off = 1; off < 256; off <<= 1) {
        int add = (t >= off) ? s[t - off] : 0;
        __syncthreads();
        s[t] += add;
        __syncthreads();
    }
    if (i < N) {
        rp[i] = s[t] - v;
        dinv[i] = rsqrtf((float)v);   // v = deg+1
    }
    if (t == 255) bsum[blockIdx.x] = s[255];
}

__global__ void k_scan2(int* __restrict__ bsum, int nb) {
    __shared__ int s[512];
    int t = threadIdx.x;
    int v = (t < nb) ? bsum[t] : 0;
    s[t] = v;
    __syncthreads();
    for (int off = 1; off < 512; off <<= 1) {
        int add = (t >= off) ? s[t - off] : 0;
        __syncthreads();
        s[t] += add;
        __syncthreads();
    }
    if (t < nb) bsum[t] = s[t] - v;
}

__global__ void k_scan3(int* __restrict__ rp, const int* __restrict__ bsum,
                        int N, int Etot) {
    int i = blockIdx.x * 256 + threadIdx.x;
    if (i < N) rp[i] += bsum[blockIdx.x];
    if (blockIdx.x == 0 && threadIdx.x == 0) rp[N] = Etot;
}

// self-loop edge: csr2[rp[u]+deg] = {u, 1/(deg+1)}
__global__ void k_self(const int* __restrict__ degi, const int* __restrict__ rp,
                       const float* __restrict__ dinv, int2* __restrict__ csr2, int N) {
    int i = blockIdx.x * 256 + threadIdx.x;
    if (i < N) {
        float d = dinv[i];
        csr2[rp[i] + degi[i]] = make_int2(i, __float_as_int(d * d));
    }
}

// atomic-free scatter fill with precomputed weight: csr2[rp[d]+pos]={s, w}
__global__ void k_fill4(const int* __restrict__ src, const int* __restrict__ dst,
                        const int* __restrict__ pos, const int* __restrict__ rp,
                        const float* __restrict__ dinv, int2* __restrict__ csr2, int E) {
    int i = blockIdx.x * 256 + threadIdx.x;
    int e = i * 4;
    if (e + 3 < E) {
        int4 s = *(const int4*)&src[e];
        int4 d = *(const int4*)&dst[e];
        int4 p = *(const int4*)&pos[e];
        float wx = dinv[s.x] * dinv[d.x];
        float wy = dinv[s.y] * dinv[d.y];
        float wz = dinv[s.z] * dinv[d.z];
        float ww = dinv[s.w] * dinv[d.w];
        csr2[rp[d.x] + p.x] = make_int2(s.x, __float_as_int(wx));
        csr2[rp[d.y] + p.y] = make_int2(s.y, __float_as_int(wy));
        csr2[rp[d.z] + p.z] = make_int2(s.z, __float_as_int(wz));
        csr2[rp[d.w] + p.w] = make_int2(s.w, __float_as_int(ww));
    } else {
        for (; e < E; ++e) {
            float wv = dinv[src[e]] * dinv[dst[e]];
            csr2[rp[dst[e]] + pos[e]] = make_int2(src[e], __float_as_int(wv));
        }
    }
}

// ---- W^T prepack: WT[n*128+k] = bf16(W[k*128+n]), once per layer ----------
__global__ void k_prepw(const float* __restrict__ W, unsigned short* __restrict__ WT) {
    int idx = blockIdx.x * 256 + threadIdx.x;   // 16384 total
    int k = idx >> 7, n = idx & 127;
    WT[n * 128 + k] = f2bf(W[idx]);             // coalesced read, scattered 2B write
}

// ---- MFMA GEMM: Y[M,128](bf16) = X[M,128] @ W[128,128] (WT prepacked) -----
#define LDA 136   // row pad +8 bf16: 2-way LDS aliasing only (free per m136)

template<bool IN_BF16>
__global__ __launch_bounds__(256) void k_gemm_mfma(const void* __restrict__ Xv,
                                                   const unsigned short* __restrict__ WT,
                                                   unsigned short* __restrict__ Y,
                                                   int M) {
    __shared__ unsigned short As[64 * LDA];    // 17.4 KB (reused for out repack)
    __shared__ unsigned short Bs[128 * LDA];   // 34.8 KB, Bs[n][k] = W[k][n]
    int t = threadIdx.x;
    int row0 = blockIdx.x * 64;

    // stage WT (bf16, coalesced uint4)
    {
        const uint4* WT4 = (const uint4*)WT;
#pragma unroll
        for (int i = 0; i < 8; ++i) {
            int idx = t + i * 256;              // 2048 uint4
            int n = idx >> 4, c8 = idx & 15;
            *(uint4*)&Bs[n * LDA + c8 * 8] = WT4[idx];
        }
    }
    if (IN_BF16) {
        const uint4* X4 = (const uint4*)Xv;
#pragma unroll
        for (int i = 0; i < 4; ++i) {
            int idx = t + i * 256;
            int r = idx >> 4, c8 = idx & 15;
            int gr = row0 + r;
            uint4 v = (gr < M) ? X4[(size_t)gr * 16 + c8] : make_uint4(0, 0, 0, 0);
            *(uint4*)&As[r * LDA + c8 * 8] = v;
        }
    } else {
        const float4* X4 = (const float4*)Xv;
#pragma unroll
        for (int i = 0; i < 8; ++i) {
            int idx = t + i * 256;
            int r = idx >> 5, c4 = idx & 31;
            int gr = row0 + r;
            float4 v = (gr < M) ? X4[(size_t)gr * 32 + c4] : make_float4(0.f, 0.f, 0.f, 0.f);
            *(unsigned*)&As[r * LDA + c4 * 4]     = packbf(v.x, v.y);
            *(unsigned*)&As[r * LDA + c4 * 4 + 2] = packbf(v.z, v.w);
        }
    }
    __syncthreads();

    int w = t >> 6, l = t & 63;
    int lr = l & 15;
    int ko = (l >> 4) * 8;

    f32x4 acc[8];
#pragma unroll
    for (int c = 0; c < 8; ++c) acc[c] = (f32x4){0.f, 0.f, 0.f, 0.f};

#pragma unroll
    for (int kc = 0; kc < 4; ++kc) {
        int kb = kc * 32 + ko;
        bf16x8 af = *(const bf16x8*)&As[(w * 16 + lr) * LDA + kb];
        bf16x8 bfr[8];
#pragma unroll
        for (int ct = 0; ct < 8; ++ct)
            bfr[ct] = *(const bf16x8*)&Bs[(ct * 16 + lr) * LDA + kb];
#pragma unroll
        for (int ct = 0; ct < 8; ++ct)
            acc[ct] = __builtin_amdgcn_mfma_f32_16x16x32_bf16(af, bfr[ct], acc[ct], 0, 0, 0);
    }

    // repack D tile through LDS (As reused), then coalesced uint4 stores
    __syncthreads();
    int qr = (l >> 4) * 4;
#pragma unroll
    for (int i = 0; i < 4; ++i) {
        int r = w * 16 + qr + i;
#pragma unroll
        for (int ct = 0; ct < 8; ++ct)
            As[r * LDA + ct * 16 + lr] = f2bf(acc[ct][i]);
    }
    __syncthreads();
    {
        uint4* Y4 = (uint4*)Y;
#pragma unroll
        for (int i = 0; i < 4; ++i) {
            int idx = t + i * 256;
            int r = idx >> 4, c8 = idx & 15;
            int gr = row0 + r;
            if (gr < M) Y4[(size_t)gr * 16 + c8] = *(const uint4*)&As[r * LDA + c8 * 8];
        }
    }
}

// ---- aggregation R5: wave-per-node, no LDS, shuffle reduce ----------------
// OUT[u] = lrelu( sum_{e in csr[u]} w[e]*H[src[e]] + bias )   (self-loop is
// a CSR edge). 64 lanes = 4 edge-groups x 16 lanes; lane gathers uint4
// (8 bf16 ch); fp32 accumulate; butterfly-reduce across groups.
__global__ __launch_bounds__(256) void k_agg4(const unsigned short* __restrict__ H,
                                              const int2* __restrict__ csr2,
                                              const int* __restrict__ rp,
                                              const float* __restrict__ bias,
                                              unsigned short* __restrict__ OUT, int N) {
    int l = threadIdx.x & 63;
    int u = blockIdx.x * 4 + (threadIdx.x >> 6);
    if (u >= N) return;
    int g = l >> 4, cl = l & 15;
    int e0 = rp[u], e1 = rp[u + 1];
    const uint4* H4 = (const uint4*)H;

    float a0 = 0.f, a1 = 0.f, a2 = 0.f, a3 = 0.f;
    float a4 = 0.f, a5 = 0.f, a6 = 0.f, a7 = 0.f;
    for (int e = e0 + g; e < e1; e += 4) {
        int2 ew = csr2[e];                       // 8B broadcast within group
        float w = __int_as_float(ew.y);
        uint4 hv = H4[(size_t)ew.x * 16 + cl];   // 256B row per group
        a0 += w * bf_lo(hv.x); a1 += w * bf_hi(hv.x);
        a2 += w * bf_lo(hv.y); a3 += w * bf_hi(hv.y);
        a4 += w * bf_lo(hv.z); a5 += w * bf_hi(hv.z);
        a6 += w * bf_lo(hv.w); a7 += w * bf_hi(hv.w);
    }
    // reduce across the 4 groups (lanes l, l^16, l^32, l^48)
    a0 += __shfl_xor(a0, 16); a0 += __shfl_xor(a0, 32);
    a1 += __shfl_xor(a1, 16); a1 += __shfl_xor(a1, 32);
    a2 += __shfl_xor(a2, 16); a2 += __shfl_xor(a2, 32);
    a3 += __shfl_xor(a3, 16); a3 += __shfl_xor(a3, 32);
    a4 += __shfl_xor(a4, 16); a4 += __shfl_xor(a4, 32);
    a5 += __shfl_xor(a5, 16); a5 += __shfl_xor(a5, 32);
    a6 += __shfl_xor(a6, 16); a6 += __shfl_xor(a6, 32);
    a7 += __shfl_xor(a7, 16); a7 += __shfl_xor(a7, 32);

    if (g == 0) {
        float4 b0 = *(const float4*)&bias[cl * 8];
        float4 b1 = *(const float4*)&bias[cl * 8 + 4];
        uint4 o;
        o.x = packbf(lrelu(a0 + b0.x), lrelu(a1 + b0.y));
        o.y = packbf(lrelu(a2 + b0.z), lrelu(a3 + b0.w));
        o.z = packbf(lrelu(a4 + b1.x), lrelu(a5 + b1.y));
        o.w = packbf(lrelu(a6 + b1.z), lrelu(a7 + b1.w));
        ((uint4*)OUT)[(size_t)u * 16 + cl] = o;
    }
}

// ---- global mean pool, node-parallel (bf16 input, fp32 accum) -------------
#define POOL_CHUNK 256
__global__ __launch_bounds__(128) void k_pool2(const unsigned short* __restrict__ H,
                                               const int* __restrict__ batch,
                                               float* __restrict__ Gsum,
                                               int* __restrict__ Gcnt, int N) {
    int n0 = blockIdx.x * POOL_CHUNK;
    int n1 = n0 + POOL_CHUNK; if (n1 > N) n1 = N;
    if (n0 >= N) return;
    int c = threadIdx.x;
    float acc = 0.f;
    int cur = batch[n0];
    int runstart = n0;
    for (int n = n0; n < n1; ++n) {
        int g = batch[n];
        if (g != cur) {
            atomicAdd(&Gsum[cur * 128 + c], acc);
            if (c == 0) atomicAdd(&Gcnt[cur], n - runstart);
            acc = 0.f; cur = g; runstart = n;
        }
        acc += bf2f(H[(size_t)n * 128 + c]);
    }
    atomicAdd(&Gsum[cur * 128 + c], acc);
    if (c == 0) atomicAdd(&Gcnt[cur], n1 - runstart);
}

// ---- fused MLP head (divide-by-count folded in): one graph per block ------
__global__ __launch_bounds__(64) void k_mlp(const float* __restrict__ Gsum,
                                            const int* __restrict__ Gcnt,
                                            const float* __restrict__ W3, const float* __restrict__ b3,
                                            const float* __restrict__ W4, const float* __restrict__ b4,
                                            const float* __restrict__ W5, const float* __restrict__ b5,
                                            float* __restrict__ OUT) {
    __shared__ float row[128];
    __shared__ float t1[64];
    __shared__ float t2[64];
    int g = blockIdx.x, t = threadIdx.x;
    float inv = 1.0f / fmaxf((float)Gcnt[g], 1.0f);
    row[t]      = Gsum[g * 128 + t] * inv;
    row[t + 64] = Gsum[g * 128 + t + 64] * inv;
    __syncthreads();
    float acc = b3[t];
    for (int k = 0; k < 128; ++k) acc += row[k] * W3[k * 64 + t];
    t1[t] = lrelu(acc);
    __syncthreads();
    acc = b4[t];
    for (int k = 0; k < 64; ++k) acc += t1[k] * W4[k * 64 + t];
    t2[t] = lrelu(acc);
    __syncthreads();
    if (t < 10) {
        acc = b5[t];
        for (int k = 0; k < 64; ++k) acc += t2[k] * W5[k * 10 + t];
        OUT[g * 10 + t] = acc;
    }
}

// ---------------------------------------------------------------------------

extern "C" void kernel_launch(void* const* d_in, const int* in_sizes, int n_in,
                              void* d_out, int out_size, void* d_ws, size_t ws_size,
                              hipStream_t stream) {
    const float* x    = (const float*)d_in[0];
    const int*   ei   = (const int*)d_in[1];   // [2, E] int32
    const int*   batch= (const int*)d_in[2];
    const float* W1   = (const float*)d_in[3];
    const float* b1   = (const float*)d_in[4];
    const float* W2   = (const float*)d_in[5];
    const float* b2   = (const float*)d_in[6];
    const float* W3   = (const float*)d_in[7];
    const float* b3   = (const float*)d_in[8];
    const float* W4   = (const float*)d_in[9];
    const float* b4   = (const float*)d_in[10];
    const float* W5   = (const float*)d_in[11];
    const float* b5   = (const float*)d_in[12];
    float* out = (float*)d_out;

    const int N = in_sizes[2];          // 100000
    const int E = in_sizes[1] / 2;      // 1600000
    const int NG = 128;                 // NUM_GRAPHS

    const int* src = ei;
    const int* dst = ei + E;

    // workspace carve-up  (degi, gsum, gcnt contiguous -> one zero pass)
    char* w = (char*)d_ws;
    unsigned short* bufA = (unsigned short*)w; w += (size_t)N * 128 * 2;  // 25.6 MB
    unsigned short* bufB = (unsigned short*)w; w += (size_t)N * 128 * 2;  // 25.6 MB
    int*   degi = (int*)w;   w += (size_t)N * 4;
    float* gsum = (float*)w; w += (size_t)NG * 128 * 4;
    int*   gcnt = (int*)w;   w += (size_t)NG * 4;
    float* dinv = (float*)w; w += (size_t)N * 4;
    int*   rp   = (int*)w;   w += (size_t)(N + 8) * 4;
    int*   bsum = (int*)w;   w += 512 * 4;
    int2*  csr2 = (int2*)w;  w += (size_t)(E + N) * 8;   // 13.6 MB
    int*   pos  = (int*)w;   w += (size_t)E * 4;         // 6.4 MB
    unsigned short* WT1 = (unsigned short*)w; w += 128 * 128 * 2;
    unsigned short* WT2 = (unsigned short*)w; w += 128 * 128 * 2;
    (void)ws_size; (void)n_in; (void)out_size;

    int nbN  = (N + 255) / 256;       // 391
    int nbE4 = (E / 4 + 255) / 256;   // 1563
    int nZero = N + NG * 128 + NG;
    int nbZ  = (nZero + 255) / 256;

    // CSR build + pool-accumulator zeroing; W prepack
    k_zero_i32<<<nbZ, 256, 0, stream>>>(degi, nZero);
    k_prepw<<<64, 256, 0, stream>>>(W1, WT1);
    k_prepw<<<64, 256, 0, stream>>>(W2, WT2);
    k_count4<<<nbE4, 256, 0, stream>>>(dst, degi, pos, E);
    k_scan1<<<nbN, 256, 0, stream>>>(degi, rp, bsum, dinv, N);
    k_scan2<<<1, 512, 0, stream>>>(bsum, nbN);
    k_scan3<<<nbN, 256, 0, stream>>>(rp, bsum, N, E + N);
    k_self<<<nbN, 256, 0, stream>>>(degi, rp, dinv, csr2, N);
    k_fill4<<<nbE4, 256, 0, stream>>>(src, dst, pos, rp, dinv, csr2, E);

    int nbG = (N + 63) / 64;          // 1563 GEMM blocks
    int nbA = (N + 3) / 4;            // 25000 agg blocks (4 waves = 4 nodes)

    // layer 1
    k_gemm_mfma<false><<<nbG, 256, 0, stream>>>(x, WT1, bufA, N);
    k_agg4<<<nbA, 256, 0, stream>>>(bufA, csr2, rp, b1, bufB, N);
    // layer 2
    k_gemm_mfma<true><<<nbG, 256, 0, stream>>>(bufB, WT2, bufA, N);
    k_agg4<<<nbA, 256, 0, stream>>>(bufA, csr2, rp, b2, bufB, N);

    // pool + MLP head
    int nbP = (N + POOL_CHUNK - 1) / POOL_CHUNK;
    k_pool2<<<nbP, 128, 0, stream>>>(bufB, batch, gsum, gcnt, N);
    k_mlp<<<NG, 64, 0, stream>>>(gsum, gcnt, W3, b3, W4, b4, W5, b5, out);
}

// Round 7
// 400.870 us; speedup vs baseline: 2.3716x; 1.1853x over previous
//
#include <hip/hip_runtime.h>
#include <hip/hip_bf16.h>

// ---------------------------------------------------------------------------
// GCN: h1 = lrelu(GCNConv(x; W1,b1)); h2 = lrelu(GCNConv(h1; W2,b2));
//      g = segment_mean(h2, batch); MLP head W3/W4/W5.
// R1: node-parallel pooling. R2: edge-parallel float4 gathers.
// R3: bf16 H; GEMMs -> MFMA 16x16x32_bf16. R4: atomic-free CSR fill.
// R5: wave-per-node agg, no LDS/barrier; weights precomputed in fill.
// R6: pool3 vectorized multi-stream (76->~12us); CSR count overlapped with
//     GEMM-1 in one kernel (independent work, hides ~30us); agg csr2
//     prefetch pipeline; launch merges (init=zero+prepw, fill+self).
// ---------------------------------------------------------------------------

#define SLOPE 0.01f

__device__ __forceinline__ float lrelu(float x) { return x > 0.f ? x : SLOPE * x; }

// bf16 helpers (RNE round, bit-shift expand)
__device__ __forceinline__ unsigned short f2bf(float f) {
    union { float f; unsigned u; } v; v.f = f;
    unsigned r = v.u + 0x7fffu + ((v.u >> 16) & 1u);
    return (unsigned short)(r >> 16);
}
__device__ __forceinline__ float bf2f(unsigned short h) {
    union { unsigned u; float f; } v; v.u = ((unsigned)h) << 16;
    return v.f;
}
__device__ __forceinline__ float bf_lo(unsigned x) {
    union { unsigned u; float f; } v; v.u = x << 16; return v.f;
}
__device__ __forceinline__ float bf_hi(unsigned x) {
    union { unsigned u; float f; } v; v.u = x & 0xffff0000u; return v.f;
}
__device__ __forceinline__ unsigned packbf(float lo, float hi) {
    return (unsigned)f2bf(lo) | ((unsigned)f2bf(hi) << 16);
}

typedef __attribute__((ext_vector_type(8))) short bf16x8;
typedef __attribute__((ext_vector_type(4))) float f32x4;

// ---- init: prepack W1^T, W2^T (bf16) + zero degi/gsum/gcnt ---------------
__global__ void k_init(int* __restrict__ zbase, int nz,
                       const float* __restrict__ W1, unsigned short* __restrict__ WT1,
                       const float* __restrict__ W2, unsigned short* __restrict__ WT2) {
    int b = blockIdx.x;
    if (b < 64) {
        int idx = b * 256 + threadIdx.x;
        int k = idx >> 7, n = idx & 127;
        WT1[n * 128 + k] = f2bf(W1[idx]);
    } else if (b < 128) {
        int idx = (b - 64) * 256 + threadIdx.x;
        int k = idx >> 7, n = idx & 127;
        WT2[n * 128 + k] = f2bf(W2[idx]);
    } else {
        int i = (b - 128) * 256 + threadIdx.x;
        if (i < nz) zbase[i] = 0;
    }
}

// ---- GEMM body: Y[M,128](bf16) = X[M,128] @ W (WT prepacked bf16) ---------
#define LDA 136   // row pad +8 bf16: 2-way LDS aliasing only (free per m136)

template<bool IN_BF16>
__device__ __forceinline__ void gemm_body(const void* __restrict__ Xv,
                                          const unsigned short* __restrict__ WT,
                                          unsigned short* __restrict__ Y, int M,
                                          unsigned short* As, unsigned short* Bs,
                                          int bid) {
    int t = threadIdx.x;
    int row0 = bid * 64;

    {
        const uint4* WT4 = (const uint4*)WT;
#pragma unroll
        for (int i = 0; i < 8; ++i) {
            int idx = t + i * 256;              // 2048 uint4
            int n = idx >> 4, c8 = idx & 15;
            *(uint4*)&Bs[n * LDA + c8 * 8] = WT4[idx];
        }
    }
    if (IN_BF16) {
        const uint4* X4 = (const uint4*)Xv;
#pragma unroll
        for (int i = 0; i < 4; ++i) {
            int idx = t + i * 256;
            int r = idx >> 4, c8 = idx & 15;
            int gr = row0 + r;
            uint4 v = (gr < M) ? X4[(size_t)gr * 16 + c8] : make_uint4(0, 0, 0, 0);
            *(uint4*)&As[r * LDA + c8 * 8] = v;
        }
    } else {
        const float4* X4 = (const float4*)Xv;
#pragma unroll
        for (int i = 0; i < 8; ++i) {
            int idx = t + i * 256;
            int r = idx >> 5, c4 = idx & 31;
            int gr = row0 + r;
            float4 v = (gr < M) ? X4[(size_t)gr * 32 + c4] : make_float4(0.f, 0.f, 0.f, 0.f);
            *(unsigned*)&As[r * LDA + c4 * 4]     = packbf(v.x, v.y);
            *(unsigned*)&As[r * LDA + c4 * 4 + 2] = packbf(v.z, v.w);
        }
    }
    __syncthreads();

    int w = t >> 6, l = t & 63;
    int lr = l & 15;
    int ko = (l >> 4) * 8;

    f32x4 acc[8];
#pragma unroll
    for (int c = 0; c < 8; ++c) acc[c] = (f32x4){0.f, 0.f, 0.f, 0.f};

#pragma unroll
    for (int kc = 0; kc < 4; ++kc) {
        int kb = kc * 32 + ko;
        bf16x8 af = *(const bf16x8*)&As[(w * 16 + lr) * LDA + kb];
        bf16x8 bfr[8];
#pragma unroll
        for (int ct = 0; ct < 8; ++ct)
            bfr[ct] = *(const bf16x8*)&Bs[(ct * 16 + lr) * LDA + kb];
#pragma unroll
        for (int ct = 0; ct < 8; ++ct)
            acc[ct] = __builtin_amdgcn_mfma_f32_16x16x32_bf16(af, bfr[ct], acc[ct], 0, 0, 0);
    }

    // repack D tile through LDS (As reused), then coalesced uint4 stores
    __syncthreads();
    int qr = (l >> 4) * 4;
#pragma unroll
    for (int i = 0; i < 4; ++i) {
        int r = w * 16 + qr + i;
#pragma unroll
        for (int ct = 0; ct < 8; ++ct)
            As[r * LDA + ct * 16 + lr] = f2bf(acc[ct][i]);
    }
    __syncthreads();
    {
        uint4* Y4 = (uint4*)Y;
#pragma unroll
        for (int i = 0; i < 4; ++i) {
            int idx = t + i * 256;
            int r = idx >> 4, c8 = idx & 15;
            int gr = row0 + r;
            if (gr < M) Y4[(size_t)gr * 16 + c8] = *(const uint4*)&As[r * LDA + c8 * 8];
        }
    }
}

// ---- count (8 edges/thread, atomicAdd return = in-bucket position) --------
__device__ __forceinline__ void count_body(const int* __restrict__ dst,
                                           int* __restrict__ degi,
                                           int* __restrict__ pos, int E, int bid) {
    int i = bid * 256 + threadIdx.x;
    int e = i * 8;
    if (e + 7 < E) {
        int4 d0 = *(const int4*)&dst[e];
        int4 d1 = *(const int4*)&dst[e + 4];
        int4 p0, p1;
        p0.x = atomicAdd(&degi[d0.x], 1);
        p0.y = atomicAdd(&degi[d0.y], 1);
        p0.z = atomicAdd(&degi[d0.z], 1);
        p0.w = atomicAdd(&degi[d0.w], 1);
        p1.x = atomicAdd(&degi[d1.x], 1);
        p1.y = atomicAdd(&degi[d1.y], 1);
        p1.z = atomicAdd(&degi[d1.z], 1);
        p1.w = atomicAdd(&degi[d1.w], 1);
        *(int4*)&pos[e]     = p0;
        *(int4*)&pos[e + 4] = p1;
    } else {
        for (; e < E; ++e) pos[e] = atomicAdd(&degi[dst[e]], 1);
    }
}

// ---- merged: CSR count (blocks 0..nbC-1) + GEMM layer 1 (rest) ------------
// Independent work: count is atomic-latency bound (VALU~0), gemm is MFMA.
__global__ __launch_bounds__(256) void k_count_gemm1(
    const int* __restrict__ dst, int* __restrict__ degi, int* __restrict__ pos,
    int E, int nbC,
    const float* __restrict__ X, const unsigned short* __restrict__ WT,
    unsigned short* __restrict__ Y, int M) {
    __shared__ unsigned short As[64 * LDA];
    __shared__ unsigned short Bs[128 * LDA];
    int b = blockIdx.x;
    if (b < nbC) count_body(dst, degi, pos, E, b);
    else gemm_body<false>((const void*)X, WT, Y, M, As, Bs, b - nbC);
}

__global__ __launch_bounds__(256) void k_gemm2(
    const void* __restrict__ Xv, const unsigned short* __restrict__ WT,
    unsigned short* __restrict__ Y, int M) {
    __shared__ unsigned short As[64 * LDA];
    __shared__ unsigned short Bs[128 * LDA];
    gemm_body<true>(Xv, WT, Y, M, As, Bs, blockIdx.x);
}

// ---- exclusive scan of (degi+1) -> rp (+1 self-loop slot); dinv folded ----
__global__ void k_scan1(const int* __restrict__ degi, int* __restrict__ rp,
                        int* __restrict__ bsum, float* __restrict__ dinv, int N) {
    __shared__ int s[256];
    int t = threadIdx.x;
    int i = blockIdx.x * 256 + t;
    int v = (i < N) ? (degi[i] + 1) : 0;
    s[t] = v;
    __syncthreads();
    for (int off = 1; off < 256; off <<= 1) {
        int add = (t >= off) ? s[t - off] : 0;
        __syncthreads();
        s[t] += add;
        __syncthreads();
    }
    if (i < N) {
        rp[i] = s[t] - v;
        dinv[i] = rsqrtf((float)v);   // v = deg+1
    }
    if (t == 255) bsum[blockIdx.x] = s[255];
}

__global__ void k_scan2(int* __restrict__ bsum, int nb) {
    __shared__ int s[512];
    int t = threadIdx.x;
    int v = (t < nb) ? bsum[t] : 0;
    s[t] = v;
    __syncthreads();
    for (int off = 1; off < 512; off <<= 1) {
        int add = (t >= off) ? s[t - off] : 0;
        __syncthreads();
        s[t] += add;
        __syncthreads();
    }
    if (t < nb) bsum[t] = s[t] - v;
}

__global__ void k_scan3(int* __restrict__ rp, const int* __restrict__ bsum,
                        int N, int Etot) {
    int i = blockIdx.x * 256 + threadIdx.x;
    if (i < N) rp[i] += bsum[blockIdx.x];
    if (blockIdx.x == 0 && threadIdx.x == 0) rp[N] = Etot;
}

// ---- merged: fill (blocks 0..nbF-1, 4 edges/thread) + self-loop edges -----
__global__ void k_fill_self(const int* __restrict__ src, const int* __restrict__ dst,
                            const int* __restrict__ pos, const int* __restrict__ rp,
                            const float* __restrict__ dinv, const int* __restrict__ degi,
                            int2* __restrict__ csr2, int E, int nbF, int N) {
    int b = blockIdx.x;
    if (b < nbF) {
        int i = b * 256 + threadIdx.x;
        int e = i * 4;
        if (e + 3 < E) {
            int4 s = *(const int4*)&src[e];
            int4 d = *(const int4*)&dst[e];
            int4 p = *(const int4*)&pos[e];
            float wx = dinv[s.x] * dinv[d.x];
            float wy = dinv[s.y] * dinv[d.y];
            float wz = dinv[s.z] * dinv[d.z];
            float ww = dinv[s.w] * dinv[d.w];
            csr2[rp[d.x] + p.x] = make_int2(s.x, __float_as_int(wx));
            csr2[rp[d.y] + p.y] = make_int2(s.y, __float_as_int(wy));
            csr2[rp[d.z] + p.z] = make_int2(s.z, __float_as_int(wz));
            csr2[rp[d.w] + p.w] = make_int2(s.w, __float_as_int(ww));
        } else {
            for (; e < E; ++e) {
                float wv = dinv[src[e]] * dinv[dst[e]];
                csr2[rp[dst[e]] + pos[e]] = make_int2(src[e], __float_as_int(wv));
            }
        }
    } else {
        int i = (b - nbF) * 256 + threadIdx.x;
        if (i < N) {
            float d = dinv[i];
            csr2[rp[i] + degi[i]] = make_int2(i, __float_as_int(d * d));
        }
    }
}

// ---- aggregation: wave-per-node, shuffle reduce, csr2 prefetch pipeline ---
__global__ __launch_bounds__(256) void k_agg4(const unsigned short* __restrict__ H,
                                              const int2* __restrict__ csr2,
                                              const int* __restrict__ rp,
                                              const float* __restrict__ bias,
                                              unsigned short* __restrict__ OUT, int N) {
    int l = threadIdx.x & 63;
    int u = blockIdx.x * 4 + (threadIdx.x >> 6);
    if (u >= N) return;
    int g = l >> 4, cl = l & 15;
    int e0 = rp[u], e1 = rp[u + 1];
    const uint4* H4 = (const uint4*)H;

    float a0 = 0.f, a1 = 0.f, a2 = 0.f, a3 = 0.f;
    float a4 = 0.f, a5 = 0.f, a6 = 0.f, a7 = 0.f;
    int e = e0 + g;
    int2 ew = make_int2(0, 0);
    if (e < e1) ew = csr2[e];
    while (e < e1) {
        int2 cur = ew;
        int en = e + 4;
        if (en < e1) ew = csr2[en];          // next entry in flight
        float w = __int_as_float(cur.y);
        uint4 hv = H4[(size_t)cur.x * 16 + cl];
        a0 += w * bf_lo(hv.x); a1 += w * bf_hi(hv.x);
        a2 += w * bf_lo(hv.y); a3 += w * bf_hi(hv.y);
        a4 += w * bf_lo(hv.z); a5 += w * bf_hi(hv.z);
        a6 += w * bf_lo(hv.w); a7 += w * bf_hi(hv.w);
        e = en;
    }
    a0 += __shfl_xor(a0, 16); a0 += __shfl_xor(a0, 32);
    a1 += __shfl_xor(a1, 16); a1 += __shfl_xor(a1, 32);
    a2 += __shfl_xor(a2, 16); a2 += __shfl_xor(a2, 32);
    a3 += __shfl_xor(a3, 16); a3 += __shfl_xor(a3, 32);
    a4 += __shfl_xor(a4, 16); a4 += __shfl_xor(a4, 32);
    a5 += __shfl_xor(a5, 16); a5 += __shfl_xor(a5, 32);
    a6 += __shfl_xor(a6, 16); a6 += __shfl_xor(a6, 32);
    a7 += __shfl_xor(a7, 16); a7 += __shfl_xor(a7, 32);

    if (g == 0) {
        float4 b0 = *(const float4*)&bias[cl * 8];
        float4 b1 = *(const float4*)&bias[cl * 8 + 4];
        uint4 o;
        o.x = packbf(lrelu(a0 + b0.x), lrelu(a1 + b0.y));
        o.y = packbf(lrelu(a2 + b0.z), lrelu(a3 + b0.w));
        o.z = packbf(lrelu(a4 + b1.x), lrelu(a5 + b1.y));
        o.w = packbf(lrelu(a6 + b1.z), lrelu(a7 + b1.w));
        ((uint4*)OUT)[(size_t)u * 16 + cl] = o;
    }
}

// ---- pool R6: 4 node-streams x 64 lanes (uint = 2ch), run-accumulate ------
#define PCH 128
__global__ __launch_bounds__(256) void k_pool3(const unsigned short* __restrict__ H,
                                               const int* __restrict__ batch,
                                               float* __restrict__ Gsum,
                                               int* __restrict__ Gcnt, int N) {
    int t = threadIdx.x;
    int st = t >> 6, c2 = t & 63;     // stream 0..3, channel pair 0..63
    int n0 = blockIdx.x * PCH + st * (PCH / 4);
    int n1 = n0 + (PCH / 4); if (n1 > N) n1 = N;
    if (n0 >= N) return;
    float a0 = 0.f, a1 = 0.f;
    int cur = batch[n0], runstart = n0;
    for (int n = n0; n < n1; ++n) {
        int g = batch[n];
        if (g != cur) {
            atomicAdd(&Gsum[cur * 128 + c2 * 2], a0);
            atomicAdd(&Gsum[cur * 128 + c2 * 2 + 1], a1);
            if (c2 == 0) atomicAdd(&Gcnt[cur], n - runstart);
            a0 = a1 = 0.f; cur = g; runstart = n;
        }
        unsigned hv = *(const unsigned*)&H[(size_t)n * 128 + c2 * 2];
        a0 += bf_lo(hv); a1 += bf_hi(hv);
    }
    atomicAdd(&Gsum[cur * 128 + c2 * 2], a0);
    atomicAdd(&Gsum[cur * 128 + c2 * 2 + 1], a1);
    if (c2 == 0) atomicAdd(&Gcnt[cur], n1 - runstart);
}

// ---- fused MLP head (divide-by-count folded in): one graph per block ------
__global__ __launch_bounds__(64) void k_mlp(const float* __restrict__ Gsum,
                                            const int* __restrict__ Gcnt,
                                            const float* __restrict__ W3, const float* __restrict__ b3,
                                            const float* __restrict__ W4, const float* __restrict__ b4,
                                            const float* __restrict__ W5, const float* __restrict__ b5,
                                            float* __restrict__ OUT) {
    __shared__ float row[128];
    __shared__ float t1[64];
    __shared__ float t2[64];
    int g = blockIdx.x, t = threadIdx.x;
    float inv = 1.0f / fmaxf((float)Gcnt[g], 1.0f);
    row[t]      = Gsum[g * 128 + t] * inv;
    row[t + 64] = Gsum[g * 128 + t + 64] * inv;
    __syncthreads();
    float acc = b3[t];
    for (int k = 0; k < 128; ++k) acc += row[k] * W3[k * 64 + t];
    t1[t] = lrelu(acc);
    __syncthreads();
    acc = b4[t];
    for (int k = 0; k < 64; ++k) acc += t1[k] * W4[k * 64 + t];
    t2[t] = lrelu(acc);
    __syncthreads();
    if (t < 10) {
        acc = b5[t];
        for (int k = 0; k < 64; ++k) acc += t2[k] * W5[k * 10 + t];
        OUT[g * 10 + t] = acc;
    }
}

// ---------------------------------------------------------------------------

extern "C" void kernel_launch(void* const* d_in, const int* in_sizes, int n_in,
                              void* d_out, int out_size, void* d_ws, size_t ws_size,
                              hipStream_t stream) {
    const float* x    = (const float*)d_in[0];
    const int*   ei   = (const int*)d_in[1];   // [2, E] int32
    const int*   batch= (const int*)d_in[2];
    const float* W1   = (const float*)d_in[3];
    const float* b1   = (const float*)d_in[4];
    const float* W2   = (const float*)d_in[5];
    const float* b2   = (const float*)d_in[6];
    const float* W3   = (const float*)d_in[7];
    const float* b3   = (const float*)d_in[8];
    const float* W4   = (const float*)d_in[9];
    const float* b4   = (const float*)d_in[10];
    const float* W5   = (const float*)d_in[11];
    const float* b5   = (const float*)d_in[12];
    float* out = (float*)d_out;

    const int N = in_sizes[2];          // 100000
    const int E = in_sizes[1] / 2;      // 1600000
    const int NG = 128;                 // NUM_GRAPHS

    const int* src = ei;
    const int* dst = ei + E;

    // workspace carve-up  (degi, gsum, gcnt contiguous -> one zero pass)
    char* w = (char*)d_ws;
    unsigned short* bufA = (unsigned short*)w; w += (size_t)N * 128 * 2;  // 25.6 MB
    unsigned short* bufB = (unsigned short*)w; w += (size_t)N * 128 * 2;  // 25.6 MB
    int*   degi = (int*)w;   w += (size_t)N * 4;
    float* gsum = (float*)w; w += (size_t)NG * 128 * 4;
    int*   gcnt = (int*)w;   w += (size_t)NG * 4;
    float* dinv = (float*)w; w += (size_t)N * 4;
    int*   rp   = (int*)w;   w += (size_t)(N + 8) * 4;
    int*   bsum = (int*)w;   w += 512 * 4;
    int2*  csr2 = (int2*)w;  w += (size_t)(E + N) * 8;   // 13.6 MB
    int*   pos  = (int*)w;   w += (size_t)E * 4;         // 6.4 MB
    unsigned short* WT1 = (unsigned short*)w; w += 128 * 128 * 2;
    unsigned short* WT2 = (unsigned short*)w; w += 128 * 128 * 2;
    (void)ws_size; (void)n_in; (void)out_size;

    int nbN  = (N + 255) / 256;       // 391
    int nbE4 = (E / 4 + 255) / 256;   // 1563 (fill)
    int nbE8 = (E / 8 + 255) / 256;   // 782  (count)
    int nbG  = (N + 63) / 64;         // 1563 (gemm)
    int nZero = N + NG * 128 + NG;
    int nbZ  = (nZero + 255) / 256;

    // init: W prepack + zero accumulators
    k_init<<<128 + nbZ, 256, 0, stream>>>(degi, nZero, W1, WT1, W2, WT2);
    // CSR count overlapped with GEMM layer 1 (independent)
    k_count_gemm1<<<nbE8 + nbG, 256, 0, stream>>>(dst, degi, pos, E, nbE8,
                                                  x, WT1, bufA, N);
    k_scan1<<<nbN, 256, 0, stream>>>(degi, rp, bsum, dinv, N);
    k_scan2<<<1, 512, 0, stream>>>(bsum, nbN);
    k_scan3<<<nbN, 256, 0, stream>>>(rp, bsum, N, E + N);
    k_fill_self<<<nbE4 + nbN, 256, 0, stream>>>(src, dst, pos, rp, dinv, degi,
                                                csr2, E, nbE4, N);

    int nbA = (N + 3) / 4;            // 25000 agg blocks (4 waves = 4 nodes)

    // layer 1 aggregate, layer 2 gemm + aggregate
    k_agg4<<<nbA, 256, 0, stream>>>(bufA, csr2, rp, b1, bufB, N);
    k_gemm2<<<nbG, 256, 0, stream>>>(bufB, WT2, bufA, N);
    k_agg4<<<nbA, 256, 0, stream>>>(bufA, csr2, rp, b2, bufB, N);

    // pool + MLP head
    int nbP = (N + PCH - 1) / PCH;    // 782
    k_pool3<<<nbP, 256, 0, stream>>>(bufB, batch, gsum, gcnt, N);
    k_mlp<<<NG, 64, 0, stream>>>(gsum, gcnt, W3, b3, W4, b4, W5, b5, out);
}